// Round 2
// baseline (6125.919 us; speedup 1.0000x reference)
//
#include <hip/hip_runtime.h>
#include <hip/hip_bf16.h>
#include <cstdint>
#include <cstddef>

// ---------------------------------------------------------------------------
// Sizes (fixed by the problem)
// ---------------------------------------------------------------------------
#define NP_N 20000
#define NA_N 20000
#define E_AP_N 400000
#define E_PP_N 400000
// D_IN=128, D_H=256, HEADS=8, D_HEAD=32, D_FF=2048, D_OUT=64

// ---------------------------------------------------------------------------
// GEMM: C(N,M) = A(N,K) @ B(M,K)^T + bias, optional relu. All row-major.
// 64x64 tile, BK=16, 256 threads, 4x4 micro-tile per thread.
// ---------------------------------------------------------------------------
__global__ __launch_bounds__(256) void gemm_bias_kernel(
    const float* __restrict__ A, const float* __restrict__ B,
    const float* __restrict__ bias, float* __restrict__ C,
    int N, int M, int K, int relu)
{
    __shared__ float As[16][68];
    __shared__ float Bs[16][68];
    int tid = threadIdx.x;
    int row0 = blockIdx.x * 64;
    int col0 = blockIdx.y * 64;
    int tx = tid & 15, ty = tid >> 4;
    float acc[4][4] = {};
    for (int k0 = 0; k0 < K; k0 += 16) {
#pragma unroll
        for (int it = 0; it < 4; ++it) {
            int e = it * 256 + tid;
            int r = e >> 4, c = e & 15;
            int gr = row0 + r;
            int gc = k0 + c;
            As[c][r] = (gr < N) ? A[(size_t)gr * K + gc] : 0.f;
            int br = col0 + r;
            Bs[c][r] = (br < M) ? B[(size_t)br * K + gc] : 0.f;
        }
        __syncthreads();
#pragma unroll
        for (int kk = 0; kk < 16; ++kk) {
            float a4[4], b4[4];
#pragma unroll
            for (int j = 0; j < 4; ++j) { a4[j] = As[kk][ty * 4 + j]; b4[j] = Bs[kk][tx * 4 + j]; }
#pragma unroll
            for (int i = 0; i < 4; ++i)
#pragma unroll
                for (int j = 0; j < 4; ++j)
                    acc[i][j] = fmaf(a4[i], b4[j], acc[i][j]);
        }
        __syncthreads();
    }
#pragma unroll
    for (int i = 0; i < 4; ++i) {
        int gr = row0 + ty * 4 + i;
        if (gr >= N) continue;
#pragma unroll
        for (int j = 0; j < 4; ++j) {
            int gc = col0 + tx * 4 + j;
            if (gc >= M) continue;
            float v = acc[i][j] + (bias ? bias[gc] : 0.f);
            if (relu) v = fmaxf(v, 0.f);
            C[(size_t)gr * M + gc] = v;
        }
    }
}

static inline void gemm(const float* A, const float* B, const float* bias, float* C,
                        int N, int M, int K, int relu, hipStream_t s)
{
    dim3 g((N + 63) / 64, (M + 63) / 64);
    hipLaunchKernelGGL(gemm_bias_kernel, g, dim3(256), 0, s, A, B, bias, C, N, M, K, relu);
}

// ---------------------------------------------------------------------------
// copy hp -> tgt[:, 0, :]   (tgt row stride 768)
// ---------------------------------------------------------------------------
__global__ void copy_col0_kernel(const float* __restrict__ src, float* __restrict__ tgt, int n)
{
    int i = blockIdx.x * blockDim.x + threadIdx.x;
    if (i >= n) return;
    int p = i >> 8, c = i & 255;
    tgt[(size_t)p * 768 + c] = src[i];
}

__global__ void zero_ints_kernel(int* __restrict__ p, int n)
{
    int i = blockIdx.x * blockDim.x + threadIdx.x;
    if (i < n) p[i] = 0;
}

// ---------------------------------------------------------------------------
// GAT attention projections: el[n,h] = sum_d h[n,h*32+d]*al[h,d]; er likewise
// ---------------------------------------------------------------------------
__global__ void attn_lr_kernel(const float* __restrict__ h, const float* __restrict__ al,
                               const float* __restrict__ ar, float* __restrict__ el,
                               float* __restrict__ er, int N)
{
    int idx = blockIdx.x * blockDim.x + threadIdx.x;
    if (idx >= N * 8) return;
    int hd = idx & 7;
    const float* hp = h + (size_t)(idx >> 3) * 256 + hd * 32;
    const float* a1 = al + hd * 32;
    const float* a2 = ar + hd * 32;
    float s1 = 0.f, s2 = 0.f;
#pragma unroll
    for (int d = 0; d < 32; ++d) { float v = hp[d]; s1 = fmaf(v, a1[d], s1); s2 = fmaf(v, a2[d], s2); }
    el[idx] = s1;
    er[idx] = s2;
}

// ---------------------------------------------------------------------------
// CSR build: degree count, exclusive scan (single block), scatter
// ---------------------------------------------------------------------------
__global__ void count_deg_kernel(const int* __restrict__ dst, int* __restrict__ deg, int E)
{
    int e = blockIdx.x * blockDim.x + threadIdx.x;
    if (e < E) atomicAdd(&deg[dst[e]], 1);
}

__global__ void exscan_kernel(const int* __restrict__ deg, int* __restrict__ offs, int N)
{
    __shared__ int sbuf[1024];
    __shared__ int carry;
    int tid = threadIdx.x;
    if (tid == 0) carry = 0;
    __syncthreads();
    for (int base = 0; base < N; base += 1024) {
        int i = base + tid;
        int v = (i < N) ? deg[i] : 0;
        sbuf[tid] = v;
        __syncthreads();
        for (int off = 1; off < 1024; off <<= 1) {
            int t = (tid >= off) ? sbuf[tid - off] : 0;
            __syncthreads();
            sbuf[tid] += t;
            __syncthreads();
        }
        if (i < N) offs[i] = carry + sbuf[tid] - v;
        int chunk_total = sbuf[1023];
        __syncthreads();
        if (tid == 0) carry += chunk_total;
        __syncthreads();
    }
    if (tid == 0) offs[N] = carry;
}

__global__ void scatter_kernel(const int* __restrict__ src, const int* __restrict__ dst,
                               const int* __restrict__ offs, int* __restrict__ cur,
                               int* __restrict__ elist, int E)
{
    int e = blockIdx.x * blockDim.x + threadIdx.x;
    if (e >= E) return;
    int d = dst[e];
    int pos = atomicAdd(&cur[d], 1);
    elist[offs[d] + pos] = src[e];
}

// ---------------------------------------------------------------------------
// GAT aggregation: one wave per destination paper.
// Self loop handled as the e==beg-1 iteration. No max-subtraction (cancels in
// the ratio; scores are O(few) so expf is safe in f32).
// ---------------------------------------------------------------------------
__global__ __launch_bounds__(64) void gat_agg_kernel(
    const float* __restrict__ h, const float* __restrict__ el, const float* __restrict__ er,
    const int* __restrict__ offs, const int* __restrict__ elist,
    const float* __restrict__ bias, float* __restrict__ out,
    int Ndst, int self_base, int out_stride, int out_coloff)
{
    int p = blockIdx.x;
    if (p >= Ndst) return;
    int l = threadIdx.x;
    int dn = self_base + p;
    float er4[4], acc[4] = {0.f, 0.f, 0.f, 0.f}, zs[4] = {0.f, 0.f, 0.f, 0.f};
#pragma unroll
    for (int j = 0; j < 4; ++j) er4[j] = er[(size_t)dn * 8 + ((l + 64 * j) >> 5)];
    int beg = offs[p], end = offs[p + 1];
    for (int e = beg - 1; e < end; ++e) {
        int s = (e < beg) ? dn : elist[e];
        const float* hs = h + (size_t)s * 256;
        const float* els = el + (size_t)s * 8;
#pragma unroll
        for (int j = 0; j < 4; ++j) {
            int c = l + 64 * j;
            float x = els[c >> 5] + er4[j];
            x = x > 0.f ? x : 0.2f * x;
            float w = expf(x);
            acc[j] = fmaf(w, hs[c], acc[j]);
            zs[j] += w;
        }
    }
#pragma unroll
    for (int j = 0; j < 4; ++j) {
        int c = l + 64 * j;
        out[(size_t)p * out_stride + out_coloff + c] = acc[j] / zs[j] + bias[c];
    }
}

// ---------------------------------------------------------------------------
// Tiny MHA: S=Sk=3, one thread per (paper, query i, head).
// ---------------------------------------------------------------------------
__global__ void mha3_kernel(const float* __restrict__ qb, int ldq, int qoff,
                            const float* __restrict__ kvb, int ldkv, int koff, int voff,
                            float* __restrict__ ob, int NPn)
{
    int idx = blockIdx.x * blockDim.x + threadIdx.x;
    if (idx >= NPn * 24) return;
    int h = idx & 7;
    int i = (idx >> 3) % 3;
    int p = idx / 24;
    const float* q = qb + (size_t)(p * 3 + i) * ldq + qoff + h * 32;
    float qr[32];
#pragma unroll
    for (int d = 0; d < 32; ++d) qr[d] = q[d];
    float s[3];
#pragma unroll
    for (int j = 0; j < 3; ++j) {
        const float* k = kvb + (size_t)(p * 3 + j) * ldkv + koff + h * 32;
        float a = 0.f;
#pragma unroll
        for (int d = 0; d < 32; ++d) a = fmaf(qr[d], k[d], a);
        s[j] = a * 0.17677669529663687f;  // 1/sqrt(32)
    }
    float m = fmaxf(s[0], fmaxf(s[1], s[2]));
    float e0 = expf(s[0] - m), e1 = expf(s[1] - m), e2 = expf(s[2] - m);
    float inv = 1.f / (e0 + e1 + e2);
    float aw[3] = {e0 * inv, e1 * inv, e2 * inv};
    float o[32] = {};
#pragma unroll
    for (int j = 0; j < 3; ++j) {
        const float* v = kvb + (size_t)(p * 3 + j) * ldkv + voff + h * 32;
#pragma unroll
        for (int d = 0; d < 32; ++d) o[d] = fmaf(aw[j], v[d], o[d]);
    }
    float* op = ob + (size_t)(p * 3 + i) * 256 + h * 32;
#pragma unroll
    for (int d = 0; d < 32; ++d) op[d] = o[d];
}

// ---------------------------------------------------------------------------
// Fused residual-add + LayerNorm over 256 channels. One wave per row.
// In-place safe (each thread reads its row fully into registers first).
// ---------------------------------------------------------------------------
__global__ __launch_bounds__(256) void add_ln_kernel(
    const float* __restrict__ a, const float* __restrict__ b,
    const float* __restrict__ g, const float* __restrict__ be,
    float* __restrict__ out, int rows)
{
    int row = blockIdx.x * 4 + (threadIdx.x >> 6);
    if (row >= rows) return;
    int l = threadIdx.x & 63;
    const float* ar = a + (size_t)row * 256;
    const float* br = b + (size_t)row * 256;
    float v[4];
    float s = 0.f;
#pragma unroll
    for (int j = 0; j < 4; ++j) { v[j] = ar[l + 64 * j] + br[l + 64 * j]; s += v[j]; }
#pragma unroll
    for (int off = 32; off; off >>= 1) s += __shfl_xor(s, off);
    float mean = s * (1.f / 256.f);
    float s2 = 0.f;
#pragma unroll
    for (int j = 0; j < 4; ++j) { float d = v[j] - mean; s2 = fmaf(d, d, s2); }
#pragma unroll
    for (int off = 32; off; off >>= 1) s2 += __shfl_xor(s2, off);
    float rstd = rsqrtf(s2 * (1.f / 256.f) + 1e-5f);
    float* orow = out + (size_t)row * 256;
#pragma unroll
    for (int j = 0; j < 4; ++j) {
        int c = l + 64 * j;
        orow[c] = (v[j] - mean) * rstd * g[c] + be[c];
    }
}

// ---------------------------------------------------------------------------
// kernel_launch — workspace layout (floats), TOTAL = 46,080,000 fl = 184.3 MB
//   tgt [0,        15.36M)  (NP,3,256) = (60000,256)
//   X   [15.36M,   30.72M)  x1 -> x2 -> z, LayerNorms in place
//   S   [30.72M,   46.08M)  chunk scratch:
//        S0 qkv (12000x768=9.216M) | S1 o (3.072M) | S2 proj (3.072M)
//        FF era: ff1 (6000x2048=12.288M) at S0, ff2-out at S2
//   GAT era overlays X+S:
//        x_ap  [15.36M,25.6M)  h_ap [25.6M,35.84M)  h_pp -> [15.36M,20.48M)
//        el/er [35.84M,36.8M)  ints [36.8M,37.69M)
// ---------------------------------------------------------------------------
extern "C" void kernel_launch(void* const* d_in, const int* in_sizes, int n_in,
                              void* d_out, int out_size, void* d_ws, size_t ws_size,
                              hipStream_t stream)
{
    const float* feat_paper  = (const float*)d_in[0];
    const float* feat_author = (const float*)d_in[1];
    const float* W_in_p  = (const float*)d_in[2];
    const float* b_in_p  = (const float*)d_in[3];
    const float* W_in_a  = (const float*)d_in[4];
    const float* b_in_a  = (const float*)d_in[5];
    const float* W_gat_ap = (const float*)d_in[6];
    const float* al_ap    = (const float*)d_in[7];
    const float* ar_ap    = (const float*)d_in[8];
    const float* b_gat_ap = (const float*)d_in[9];
    const float* W_gat_pp = (const float*)d_in[10];
    const float* al_pp    = (const float*)d_in[11];
    const float* ar_pp    = (const float*)d_in[12];
    const float* b_gat_pp = (const float*)d_in[13];
    const float* Wqkv_s = (const float*)d_in[14];
    const float* bqkv_s = (const float*)d_in[15];
    const float* Wo_s   = (const float*)d_in[16];
    const float* bo_s   = (const float*)d_in[17];
    const float* Wqkv_c = (const float*)d_in[18];
    const float* bqkv_c = (const float*)d_in[19];
    const float* Wo_c   = (const float*)d_in[20];
    const float* bo_c   = (const float*)d_in[21];
    const float* W_ff1  = (const float*)d_in[22];
    const float* b_ff1  = (const float*)d_in[23];
    const float* W_ff2  = (const float*)d_in[24];
    const float* b_ff2  = (const float*)d_in[25];
    const float* ln1_g  = (const float*)d_in[26];
    const float* ln1_b  = (const float*)d_in[27];
    const float* ln2_g  = (const float*)d_in[28];
    const float* ln2_b  = (const float*)d_in[29];
    const float* ln3_g  = (const float*)d_in[30];
    const float* ln3_b  = (const float*)d_in[31];
    const float* W_pred = (const float*)d_in[32];
    const float* b_pred = (const float*)d_in[33];
    const int* ap_src = (const int*)d_in[34];
    const int* ap_dst = (const int*)d_in[35];
    const int* pp_src = (const int*)d_in[36];
    const int* pp_dst = (const int*)d_in[37];

    const int NP = NP_N, NA = NA_N;
    const int R3 = NP * 3;  // 60000

    float* ws  = (float*)d_ws;
    const size_t M1 = 15360000;  // floats per (60000,256) block
    float* tgt = ws;
    float* X   = ws + M1;
    float* S0  = ws + 2 * M1;                 // 9.216M qkv chunk
    float* S1  = S0 + (size_t)12000 * 768;    // 3.072M o chunk
    float* S2  = S1 + (size_t)12000 * 256;    // 3.072M proj chunk

    // GAT-era overlay (X and S are dead during GAT phase)
    float* x_ap = X;                          // (40000,256)
    float* hp_  = x_ap + (size_t)NA * 256;    // papers half of x_ap
    float* h_ap = x_ap + (size_t)40000 * 256; // (40000,256) at ws+25.6M
    float* h_pp = x_ap;                       // overwrites dead author half after h_ap GEMM
    float* el_ap = h_ap + (size_t)40000 * 256;  // ws+35.84M
    float* er_ap = el_ap + 320000;
    float* el_pp = er_ap + 320000;
    float* er_pp = el_pp + 160000;
    int* ireg    = (int*)(er_pp + 160000);    // ws+36.8M
    int* ap_offs = ireg;                      // 20001
    int* pp_offs = ireg + 20001;              // 20001
    int* ap_cur  = ireg + 40002;              // 20000
    int* pp_cur  = ireg + 60002;              // 20000 (contiguous with ap_cur)
    int* ap_list = ireg + 80002;              // 400000
    int* pp_list = ireg + 480002;             // 400000

    // ---- input projections ----
    gemm(feat_author, W_in_a, b_in_a, x_ap, NA, 256, 128, 0, stream);
    gemm(feat_paper,  W_in_p, b_in_p, hp_,  NP, 256, 128, 0, stream);

    // tgt[:,0,:] = hp
    {
        int n = NP * 256;
        hipLaunchKernelGGL(copy_col0_kernel, dim3((n + 255) / 256), dim3(256), 0, stream, hp_, tgt, n);
    }

    // ---- GAT feature transforms (GATConv fc has no bias) ----
    gemm(x_ap, W_gat_ap, nullptr, h_ap, NA + NP, 256, 256, 0, stream);
    gemm(hp_,  W_gat_pp, nullptr, h_pp, NP,      256, 256, 0, stream);  // overwrites dead ha region

    // ---- attention coefficient projections ----
    hipLaunchKernelGGL(attn_lr_kernel, dim3((40000 * 8 + 255) / 256), dim3(256), 0, stream,
                       h_ap, al_ap, ar_ap, el_ap, er_ap, 40000);
    hipLaunchKernelGGL(attn_lr_kernel, dim3((20000 * 8 + 255) / 256), dim3(256), 0, stream,
                       h_pp, al_pp, ar_pp, el_pp, er_pp, 20000);

    // ---- CSR build (dst -> list of src) for both edge sets ----
    hipLaunchKernelGGL(zero_ints_kernel, dim3((40000 + 255) / 256), dim3(256), 0, stream, ap_cur, 40000);
    hipLaunchKernelGGL(count_deg_kernel, dim3((E_AP_N + 255) / 256), dim3(256), 0, stream, ap_dst, ap_cur, E_AP_N);
    hipLaunchKernelGGL(count_deg_kernel, dim3((E_PP_N + 255) / 256), dim3(256), 0, stream, pp_dst, pp_cur, E_PP_N);
    hipLaunchKernelGGL(exscan_kernel, dim3(1), dim3(1024), 0, stream, ap_cur, ap_offs, NP);
    hipLaunchKernelGGL(exscan_kernel, dim3(1), dim3(1024), 0, stream, pp_cur, pp_offs, NP);
    hipLaunchKernelGGL(zero_ints_kernel, dim3((40000 + 255) / 256), dim3(256), 0, stream, ap_cur, 40000);
    hipLaunchKernelGGL(scatter_kernel, dim3((E_AP_N + 255) / 256), dim3(256), 0, stream,
                       ap_src, ap_dst, ap_offs, ap_cur, ap_list, E_AP_N);
    hipLaunchKernelGGL(scatter_kernel, dim3((E_PP_N + 255) / 256), dim3(256), 0, stream,
                       pp_src, pp_dst, pp_offs, pp_cur, pp_list, E_PP_N);

    // ---- GAT aggregation -> tgt[:,1,:] and tgt[:,2,:] ----
    hipLaunchKernelGGL(gat_agg_kernel, dim3(NP), dim3(64), 0, stream,
                       h_ap, el_ap, er_ap, ap_offs, ap_list, b_gat_ap, tgt, NP, NA, 768, 256);
    hipLaunchKernelGGL(gat_agg_kernel, dim3(NP), dim3(64), 0, stream,
                       h_pp, el_pp, er_pp, pp_offs, pp_list, b_gat_pp, tgt, NP, 0, 768, 512);

    // ---- self attention: 5 chunks of 12000 rows (4000 papers) ----
    for (int c = 0; c < 5; ++c) {
        const size_t ro = (size_t)c * 12000 * 256;
        gemm(tgt + ro, Wqkv_s, bqkv_s, S0, 12000, 768, 256, 0, stream);
        hipLaunchKernelGGL(mha3_kernel, dim3((4000 * 24 + 255) / 256), dim3(256), 0, stream,
                           S0, 768, 0, S0, 768, 256, 512, S1, 4000);
        gemm(S1, Wo_s, bo_s, S2, 12000, 256, 256, 0, stream);
        hipLaunchKernelGGL(add_ln_kernel, dim3(12000 / 4), dim3(256), 0, stream,
                           tgt + ro, S2, ln1_g, ln1_b, X + ro, 12000);
    }

    // ---- cross attention (q from X=x1, k/v from tgt), in-place LN2 ----
    float* qb  = S0;
    float* kvb = S0 + (size_t)12000 * 256;
    for (int c = 0; c < 5; ++c) {
        const size_t ro = (size_t)c * 12000 * 256;
        gemm(X + ro,   Wqkv_c,                     bqkv_c,       qb,  12000, 256, 256, 0, stream);
        gemm(tgt + ro, Wqkv_c + (size_t)256 * 256, bqkv_c + 256, kvb, 12000, 512, 256, 0, stream);
        hipLaunchKernelGGL(mha3_kernel, dim3((4000 * 24 + 255) / 256), dim3(256), 0, stream,
                           qb, 256, 0, kvb, 512, 0, 256, S1, 4000);
        gemm(S1, Wo_c, bo_c, S2, 12000, 256, 256, 0, stream);
        hipLaunchKernelGGL(add_ln_kernel, dim3(12000 / 4), dim3(256), 0, stream,
                           X + ro, S2, ln2_g, ln2_b, X + ro, 12000);
    }

    // ---- feed-forward: 10 chunks of 6000 rows, in-place LN3 ----
    for (int c = 0; c < 10; ++c) {
        const size_t ro = (size_t)c * 6000 * 256;
        gemm(X + ro, W_ff1, b_ff1, S0, 6000, 2048, 256, 1, stream);   // relu
        gemm(S0, W_ff2, b_ff2, S2, 6000, 256, 2048, 0, stream);
        hipLaunchKernelGGL(add_ln_kernel, dim3(6000 / 4), dim3(256), 0, stream,
                           X + ro, S2, ln3_g, ln3_b, X + ro, 6000);
    }

    // ---- prediction head: (20000,768) @ (64,768)^T -> d_out ----
    gemm(X, W_pred, b_pred, (float*)d_out, NP, 64, 768, 0, stream);
}

// Round 3
// 1432.254 us; speedup vs baseline: 4.2771x; 4.2771x over previous
//
#include <hip/hip_runtime.h>
#include <hip/hip_bf16.h>
#include <cstdint>
#include <cstddef>

#define NP_N 20000
#define NA_N 20000
#define E_AP_N 400000
#define E_PP_N 400000
// D_IN=128, D_H=256, HEADS=8, D_HEAD=32, D_FF=2048, D_OUT=64

typedef __attribute__((ext_vector_type(8))) short bf16x8;
typedef __attribute__((ext_vector_type(4))) float f32x4;

__device__ __forceinline__ float b2f(ushort u) { return __uint_as_float(((uint32_t)u) << 16); }
__device__ __forceinline__ ushort f2b(float f) {
    uint32_t x = __float_as_uint(f);
    return (ushort)((x + 0x7fffu + ((x >> 16) & 1u)) >> 16);  // RNE (no NaN inputs here)
}

// ---------------------------------------------------------------------------
// f32 -> bf16 convert (n multiple of 4)
// ---------------------------------------------------------------------------
__global__ void cvt_kernel(const float* __restrict__ in, ushort* __restrict__ out, int n4)
{
    int i = blockIdx.x * blockDim.x + threadIdx.x;
    if (i >= n4) return;
    float4 v = ((const float4*)in)[i];
    ushort4 o;
    o.x = f2b(v.x); o.y = f2b(v.y); o.z = f2b(v.z); o.w = f2b(v.w);
    ((ushort4*)out)[i] = o;
}

// ---------------------------------------------------------------------------
// bf16 MFMA GEMM: C(N,M) = A(N,K) @ B(M,K)^T + bias.
// 128x128 tile, BK=32, 256 threads (4 waves, 2x2), 4x4 16x16 frags per wave.
// LDS k-major [ks][row]: conflict-free ds_read_b128; staged via
// global_load_lds width 16 (uniform LDS base + lane*16, per-lane global src).
// OUT_MODE: 0 = bf16, 1 = f32, 2 = bf16 + relu
// ---------------------------------------------------------------------------
template <int OUT_MODE>
__global__ __launch_bounds__(256) void gemm_mfma(
    const ushort* __restrict__ A, const ushort* __restrict__ B,
    const float* __restrict__ bias, void* __restrict__ Cv,
    int N, int M, int K)
{
    __shared__ __align__(16) ushort Abuf[4][128 * 8];
    __shared__ __align__(16) ushort Bbuf[4][128 * 8];
    const int tid = threadIdx.x;
    const int lane = tid & 63;
    const int w = tid >> 6;
    const int wr = w >> 1, wc = w & 1;
    const int row0 = blockIdx.x * 128;
    const int col0 = blockIdx.y * 128;
    f32x4 acc[4][4] = {};

    for (int k0 = 0; k0 < K; k0 += 32) {
        // stage: 16 chunks of 1024B; wave w handles chunks w*4..w*4+3
#pragma unroll
        for (int i = 0; i < 4; ++i) {
            int c = w * 4 + i;
            int ks = c & 3;
            int rowhalf = (c >> 2) & 1;
            int r = rowhalf * 64 + lane;
            const ushort* src;
            ushort* dst;
            if (c < 8) {
                int gr = row0 + r; if (gr > N - 1) gr = N - 1;
                src = A + (size_t)gr * K + k0 + ks * 8;
                dst = &Abuf[ks][rowhalf * 64 * 8];
            } else {
                int gc = col0 + r; if (gc > M - 1) gc = M - 1;
                src = B + (size_t)gc * K + k0 + ks * 8;
                dst = &Bbuf[ks][rowhalf * 64 * 8];
            }
            __builtin_amdgcn_global_load_lds(
                (const __attribute__((address_space(1))) void*)src,
                (__attribute__((address_space(3))) void*)dst, 16, 0, 0);
        }
        __syncthreads();

        bf16x8 af[4], bfr[4];
        const int ks = lane >> 4;
        const int rl = lane & 15;
#pragma unroll
        for (int m = 0; m < 4; ++m)
            af[m] = *(const bf16x8*)&Abuf[ks][(wr * 64 + m * 16 + rl) * 8];
#pragma unroll
        for (int n = 0; n < 4; ++n)
            bfr[n] = *(const bf16x8*)&Bbuf[ks][(wc * 64 + n * 16 + rl) * 8];
#pragma unroll
        for (int m = 0; m < 4; ++m)
#pragma unroll
            for (int n = 0; n < 4; ++n)
                acc[m][n] = __builtin_amdgcn_mfma_f32_16x16x32_bf16(af[m], bfr[n], acc[m][n], 0, 0, 0);
        __syncthreads();
    }

    // epilogue: C/D layout col=lane&15, row=(lane>>4)*4+reg
#pragma unroll
    for (int m = 0; m < 4; ++m) {
#pragma unroll
        for (int n = 0; n < 4; ++n) {
            int gc = col0 + wc * 64 + n * 16 + (lane & 15);
            if (gc >= M) continue;
            float bv = bias ? bias[gc] : 0.f;
#pragma unroll
            for (int r = 0; r < 4; ++r) {
                int grow = row0 + wr * 64 + m * 16 + (lane >> 4) * 4 + r;
                if (grow >= N) continue;
                float v = acc[m][n][r] + bv;
                if (OUT_MODE == 2) v = fmaxf(v, 0.f);
                if (OUT_MODE == 1) ((float*)Cv)[(size_t)grow * M + gc] = v;
                else ((ushort*)Cv)[(size_t)grow * M + gc] = f2b(v);
            }
        }
    }
}

static inline void gemm_bf(const ushort* A, const ushort* B, const float* bias, void* C,
                           int N, int M, int K, int mode, hipStream_t s)
{
    dim3 g((N + 127) / 128, (M + 127) / 128);
    if (mode == 0)      gemm_mfma<0><<<g, 256, 0, s>>>(A, B, bias, C, N, M, K);
    else if (mode == 1) gemm_mfma<1><<<g, 256, 0, s>>>(A, B, bias, C, N, M, K);
    else                gemm_mfma<2><<<g, 256, 0, s>>>(A, B, bias, C, N, M, K);
}

// ---------------------------------------------------------------------------
// copy hp(bf16) -> tgt[:,0,:]  (tgt row stride 768), ushort4 per thread
// ---------------------------------------------------------------------------
__global__ void copy_col0_kernel(const ushort* __restrict__ src, ushort* __restrict__ tgt, int n)
{
    int i = blockIdx.x * blockDim.x + threadIdx.x;
    if (i >= n) return;  // n = NP*64
    int p = i >> 6, c = i & 63;
    ((ushort4*)tgt)[(size_t)p * 192 + c] = ((const ushort4*)src)[(size_t)p * 64 + c];
}

__global__ void zero_ints_kernel(int* __restrict__ p, int n)
{
    int i = blockIdx.x * blockDim.x + threadIdx.x;
    if (i < n) p[i] = 0;
}

// ---------------------------------------------------------------------------
// GAT el/er projections from bf16 h
// ---------------------------------------------------------------------------
__global__ void attn_lr_kernel(const ushort* __restrict__ h, const float* __restrict__ al,
                               const float* __restrict__ ar, float* __restrict__ el,
                               float* __restrict__ er, int N)
{
    int idx = blockIdx.x * blockDim.x + threadIdx.x;
    if (idx >= N * 8) return;
    int hd = idx & 7;
    const ushort* hp = h + (size_t)(idx >> 3) * 256 + hd * 32;
    const float* a1 = al + hd * 32;
    const float* a2 = ar + hd * 32;
    float s1 = 0.f, s2 = 0.f;
#pragma unroll
    for (int j = 0; j < 8; ++j) {
        ushort4 t = ((const ushort4*)hp)[j];
        float v0 = b2f(t.x), v1 = b2f(t.y), v2 = b2f(t.z), v3 = b2f(t.w);
        s1 = fmaf(v0, a1[j * 4 + 0], s1); s2 = fmaf(v0, a2[j * 4 + 0], s2);
        s1 = fmaf(v1, a1[j * 4 + 1], s1); s2 = fmaf(v1, a2[j * 4 + 1], s2);
        s1 = fmaf(v2, a1[j * 4 + 2], s1); s2 = fmaf(v2, a2[j * 4 + 2], s2);
        s1 = fmaf(v3, a1[j * 4 + 3], s1); s2 = fmaf(v3, a2[j * 4 + 3], s2);
    }
    el[idx] = s1;
    er[idx] = s2;
}

// ---------------------------------------------------------------------------
// CSR build
// ---------------------------------------------------------------------------
__global__ void count_deg_kernel(const int* __restrict__ dst, int* __restrict__ deg, int E)
{
    int e = blockIdx.x * blockDim.x + threadIdx.x;
    if (e < E) atomicAdd(&deg[dst[e]], 1);
}

__global__ void exscan_kernel(const int* __restrict__ deg, int* __restrict__ offs, int N)
{
    __shared__ int sbuf[1024];
    __shared__ int carry;
    int tid = threadIdx.x;
    if (tid == 0) carry = 0;
    __syncthreads();
    for (int base = 0; base < N; base += 1024) {
        int i = base + tid;
        int v = (i < N) ? deg[i] : 0;
        sbuf[tid] = v;
        __syncthreads();
        for (int off = 1; off < 1024; off <<= 1) {
            int t = (tid >= off) ? sbuf[tid - off] : 0;
            __syncthreads();
            sbuf[tid] += t;
            __syncthreads();
        }
        if (i < N) offs[i] = carry + sbuf[tid] - v;
        int chunk_total = sbuf[1023];
        __syncthreads();
        if (tid == 0) carry += chunk_total;
        __syncthreads();
    }
    if (tid == 0) offs[N] = carry;
}

__global__ void scatter_kernel(const int* __restrict__ src, const int* __restrict__ dst,
                               const int* __restrict__ offs, int* __restrict__ cur,
                               int* __restrict__ elist, int E)
{
    int e = blockIdx.x * blockDim.x + threadIdx.x;
    if (e >= E) return;
    int d = dst[e];
    int pos = atomicAdd(&cur[d], 1);
    elist[offs[d] + pos] = src[e];
}

// ---------------------------------------------------------------------------
// GAT aggregation: one wave per dst paper; lane owns 4 consecutive cols,
// so head = lane>>3 is uniform per lane -> one exp per edge per lane.
// ---------------------------------------------------------------------------
__global__ __launch_bounds__(64) void gat_agg_kernel(
    const ushort* __restrict__ h, const float* __restrict__ el, const float* __restrict__ er,
    const int* __restrict__ offs, const int* __restrict__ elist,
    const float* __restrict__ bias, ushort* __restrict__ out,
    int Ndst, int self_base, int out_coloff)
{
    int p = blockIdx.x;
    if (p >= Ndst) return;
    int l = threadIdx.x;
    int head = l >> 3;
    int dn = self_base + p;
    float erv = er[(size_t)dn * 8 + head];
    float acc[4] = {0.f, 0.f, 0.f, 0.f};
    float z = 0.f;
    int beg = offs[p], end = offs[p + 1];
    for (int e = beg - 1; e < end; ++e) {
        int s = (e < beg) ? dn : elist[e];
        float x = el[(size_t)s * 8 + head] + erv;
        x = x > 0.f ? x : 0.2f * x;
        float wgt = expf(x);
        z += wgt;
        ushort4 hv = *(const ushort4*)&h[(size_t)s * 256 + l * 4];
        acc[0] = fmaf(wgt, b2f(hv.x), acc[0]);
        acc[1] = fmaf(wgt, b2f(hv.y), acc[1]);
        acc[2] = fmaf(wgt, b2f(hv.z), acc[2]);
        acc[3] = fmaf(wgt, b2f(hv.w), acc[3]);
    }
    float inv = 1.f / z;
    ushort4 o;
    o.x = f2b(acc[0] * inv + bias[l * 4 + 0]);
    o.y = f2b(acc[1] * inv + bias[l * 4 + 1]);
    o.z = f2b(acc[2] * inv + bias[l * 4 + 2]);
    o.w = f2b(acc[3] * inv + bias[l * 4 + 3]);
    *(ushort4*)&out[(size_t)p * 768 + out_coloff + l * 4] = o;
}

// ---------------------------------------------------------------------------
// Tiny MHA (S=Sk=3): one thread per (paper, query, head); bf16 in/out.
// ---------------------------------------------------------------------------
__global__ void mha3_kernel(const ushort* __restrict__ qb, int ldq, int qoff,
                            const ushort* __restrict__ kvb, int ldkv, int koff, int voff,
                            ushort* __restrict__ ob, int NPn)
{
    int idx = blockIdx.x * blockDim.x + threadIdx.x;
    if (idx >= NPn * 24) return;
    int h = idx & 7;
    int i = (idx >> 3) % 3;
    int p = idx / 24;
    float qr[32];
    {
        const ushort* q = qb + (size_t)(p * 3 + i) * ldq + qoff + h * 32;
#pragma unroll
        for (int j = 0; j < 8; ++j) {
            ushort4 t = ((const ushort4*)q)[j];
            qr[j * 4 + 0] = b2f(t.x); qr[j * 4 + 1] = b2f(t.y);
            qr[j * 4 + 2] = b2f(t.z); qr[j * 4 + 3] = b2f(t.w);
        }
    }
    float s[3];
#pragma unroll
    for (int j = 0; j < 3; ++j) {
        const ushort* k = kvb + (size_t)(p * 3 + j) * ldkv + koff + h * 32;
        float a = 0.f;
#pragma unroll
        for (int t4 = 0; t4 < 8; ++t4) {
            ushort4 t = ((const ushort4*)k)[t4];
            a = fmaf(qr[t4 * 4 + 0], b2f(t.x), a);
            a = fmaf(qr[t4 * 4 + 1], b2f(t.y), a);
            a = fmaf(qr[t4 * 4 + 2], b2f(t.z), a);
            a = fmaf(qr[t4 * 4 + 3], b2f(t.w), a);
        }
        s[j] = a * 0.17677669529663687f;
    }
    float m = fmaxf(s[0], fmaxf(s[1], s[2]));
    float e0 = expf(s[0] - m), e1 = expf(s[1] - m), e2 = expf(s[2] - m);
    float inv = 1.f / (e0 + e1 + e2);
    float aw[3] = {e0 * inv, e1 * inv, e2 * inv};
    float o[32] = {};
#pragma unroll
    for (int j = 0; j < 3; ++j) {
        const ushort* v = kvb + (size_t)(p * 3 + j) * ldkv + voff + h * 32;
#pragma unroll
        for (int t4 = 0; t4 < 8; ++t4) {
            ushort4 t = ((const ushort4*)v)[t4];
            o[t4 * 4 + 0] = fmaf(aw[j], b2f(t.x), o[t4 * 4 + 0]);
            o[t4 * 4 + 1] = fmaf(aw[j], b2f(t.y), o[t4 * 4 + 1]);
            o[t4 * 4 + 2] = fmaf(aw[j], b2f(t.z), o[t4 * 4 + 2]);
            o[t4 * 4 + 3] = fmaf(aw[j], b2f(t.w), o[t4 * 4 + 3]);
        }
    }
    ushort* op = ob + (size_t)(p * 3 + i) * 256 + h * 32;
#pragma unroll
    for (int t4 = 0; t4 < 8; ++t4) {
        ushort4 t;
        t.x = f2b(o[t4 * 4 + 0]); t.y = f2b(o[t4 * 4 + 1]);
        t.z = f2b(o[t4 * 4 + 2]); t.w = f2b(o[t4 * 4 + 3]);
        ((ushort4*)op)[t4] = t;
    }
}

// ---------------------------------------------------------------------------
// Fused residual add + LayerNorm (256 ch), bf16 in/out, wave per row.
// Lane owns 4 consecutive cols. In-place safe.
// ---------------------------------------------------------------------------
__global__ __launch_bounds__(256) void add_ln_kernel(
    const ushort* __restrict__ a, const ushort* __restrict__ b,
    const float* __restrict__ g, const float* __restrict__ be,
    ushort* __restrict__ out, int rows)
{
    int row = blockIdx.x * 4 + (threadIdx.x >> 6);
    if (row >= rows) return;
    int l = threadIdx.x & 63;
    ushort4 va = *(const ushort4*)&a[(size_t)row * 256 + l * 4];
    ushort4 vb = *(const ushort4*)&b[(size_t)row * 256 + l * 4];
    float v[4];
    v[0] = b2f(va.x) + b2f(vb.x);
    v[1] = b2f(va.y) + b2f(vb.y);
    v[2] = b2f(va.z) + b2f(vb.z);
    v[3] = b2f(va.w) + b2f(vb.w);
    float s = v[0] + v[1] + v[2] + v[3];
#pragma unroll
    for (int off = 32; off; off >>= 1) s += __shfl_xor(s, off);
    float mean = s * (1.f / 256.f);
    float s2 = 0.f;
#pragma unroll
    for (int j = 0; j < 4; ++j) { float d = v[j] - mean; s2 = fmaf(d, d, s2); }
#pragma unroll
    for (int off = 32; off; off >>= 1) s2 += __shfl_xor(s2, off);
    float rstd = rsqrtf(s2 * (1.f / 256.f) + 1e-5f);
    ushort4 o;
    o.x = f2b((v[0] - mean) * rstd * g[l * 4 + 0] + be[l * 4 + 0]);
    o.y = f2b((v[1] - mean) * rstd * g[l * 4 + 1] + be[l * 4 + 1]);
    o.z = f2b((v[2] - mean) * rstd * g[l * 4 + 2] + be[l * 4 + 2]);
    o.w = f2b((v[3] - mean) * rstd * g[l * 4 + 3] + be[l * 4 + 3]);
    *(ushort4*)&out[(size_t)row * 256 + l * 4] = o;
}

// ---------------------------------------------------------------------------
// kernel_launch — ws budget 184.32 MB (proven safe).
// [0, 30.72M)     tgt_bf (60000x256 bf16)
// [30.72, 61.44M) X_bf
// [61.44, 65.08M) weights bf16
// [65.08, 184.32M) BIG (119.24 MB), era-overlaid
// ---------------------------------------------------------------------------
extern "C" void kernel_launch(void* const* d_in, const int* in_sizes, int n_in,
                              void* d_out, int out_size, void* d_ws, size_t ws_size,
                              hipStream_t stream)
{
    const float* feat_paper  = (const float*)d_in[0];
    const float* feat_author = (const float*)d_in[1];
    const float* W_in_p  = (const float*)d_in[2];
    const float* b_in_p  = (const float*)d_in[3];
    const float* W_in_a  = (const float*)d_in[4];
    const float* b_in_a  = (const float*)d_in[5];
    const float* W_gat_ap = (const float*)d_in[6];
    const float* al_ap    = (const float*)d_in[7];
    const float* ar_ap    = (const float*)d_in[8];
    const float* b_gat_ap = (const float*)d_in[9];
    const float* W_gat_pp = (const float*)d_in[10];
    const float* al_pp    = (const float*)d_in[11];
    const float* ar_pp    = (const float*)d_in[12];
    const float* b_gat_pp = (const float*)d_in[13];
    const float* Wqkv_s = (const float*)d_in[14];
    const float* bqkv_s = (const float*)d_in[15];
    const float* Wo_s   = (const float*)d_in[16];
    const float* bo_s   = (const float*)d_in[17];
    const float* Wqkv_c = (const float*)d_in[18];
    const float* bqkv_c = (const float*)d_in[19];
    const float* Wo_c   = (const float*)d_in[20];
    const float* bo_c   = (const float*)d_in[21];
    const float* W_ff1  = (const float*)d_in[22];
    const float* b_ff1  = (const float*)d_in[23];
    const float* W_ff2  = (const float*)d_in[24];
    const float* b_ff2  = (const float*)d_in[25];
    const float* ln1_g  = (const float*)d_in[26];
    const float* ln1_b  = (const float*)d_in[27];
    const float* ln2_g  = (const float*)d_in[28];
    const float* ln2_b  = (const float*)d_in[29];
    const float* ln3_g  = (const float*)d_in[30];
    const float* ln3_b  = (const float*)d_in[31];
    const float* W_pred = (const float*)d_in[32];
    const float* b_pred = (const float*)d_in[33];
    const int* ap_src = (const int*)d_in[34];
    const int* ap_dst = (const int*)d_in[35];
    const int* pp_src = (const int*)d_in[36];
    const int* pp_dst = (const int*)d_in[37];

    const int NP = NP_N, NA = NA_N;

    uint8_t* wsb = (uint8_t*)d_ws;
    ushort* tgt_bf = (ushort*)wsb;
    ushort* X_bf   = (ushort*)(wsb + 30720000);
    ushort* WB     = (ushort*)(wsb + 61440000);
    // weight offsets (elems)
    ushort* w_in_p  = WB + 0;
    ushort* w_in_a  = WB + 32768;
    ushort* w_gat_ap = WB + 65536;
    ushort* w_gat_pp = WB + 131072;
    ushort* w_qkv_s = WB + 196608;
    ushort* w_o_s   = WB + 393216;
    ushort* w_qkv_c = WB + 458752;
    ushort* w_o_c   = WB + 655360;
    ushort* w_ff1   = WB + 720896;
    ushort* w_ff2   = WB + 1245184;
    ushort* w_pred  = WB + 1769472;
    uint8_t* BIG = wsb + 65080000;

    // ---- weight + feature converts ----
    auto cvt = [&](const float* in, ushort* out, int n) {
        int n4 = n / 4;
        cvt_kernel<<<(n4 + 255) / 256, 256, 0, stream>>>(in, out, n4);
    };
    // era A overlay inside BIG
    ushort* feat_p_bf = (ushort*)BIG;                         // 5.12 MB
    ushort* feat_a_bf = (ushort*)(BIG + 5120000);             // 5.12 MB
    ushort* x_ap_bf   = (ushort*)(BIG + 10240000);            // 20.48 MB [ha; hp]
    ushort* hp_bf     = x_ap_bf + (size_t)NA * 256;
    ushort* h_ap_bf   = (ushort*)(BIG + 30720000);            // 20.48 MB
    ushort* h_pp_bf   = (ushort*)(BIG + 51200000);            // 10.24 MB
    float* el_ap = (float*)(BIG + 61440000);                  // 1.28 MB
    float* er_ap = (float*)(BIG + 62720000);
    float* el_pp = (float*)(BIG + 64000000);                  // 0.64 MB
    float* er_pp = (float*)(BIG + 64640000);
    int* ireg    = (int*)(BIG + 65280000);
    int* ap_offs = ireg;              // 20001
    int* pp_offs = ireg + 20001;      // 20001
    int* ap_cur  = ireg + 40002;      // 20000
    int* pp_cur  = ireg + 60002;      // 20000 (contiguous with ap_cur)
    int* ap_list = ireg + 80002;      // 400000
    int* pp_list = ireg + 480002;     // 400000

    cvt(feat_paper,  feat_p_bf, NP * 128);
    cvt(feat_author, feat_a_bf, NA * 128);
    cvt(W_in_p, w_in_p, 32768);
    cvt(W_in_a, w_in_a, 32768);
    cvt(W_gat_ap, w_gat_ap, 65536);
    cvt(W_gat_pp, w_gat_pp, 65536);
    cvt(Wqkv_s, w_qkv_s, 196608);
    cvt(Wo_s, w_o_s, 65536);
    cvt(Wqkv_c, w_qkv_c, 196608);
    cvt(Wo_c, w_o_c, 65536);
    cvt(W_ff1, w_ff1, 524288);
    cvt(W_ff2, w_ff2, 524288);
    cvt(W_pred, w_pred, 49152);

    // ---- input projections (bf16 out) ----
    gemm_bf(feat_a_bf, w_in_a, b_in_a, x_ap_bf, NA, 256, 128, 0, stream);
    gemm_bf(feat_p_bf, w_in_p, b_in_p, hp_bf,   NP, 256, 128, 0, stream);

    // tgt[:,0,:] = hp
    copy_col0_kernel<<<(NP * 64 + 255) / 256, 256, 0, stream>>>(hp_bf, tgt_bf, NP * 64);

    // ---- GAT feature transforms (no bias) ----
    gemm_bf(x_ap_bf, w_gat_ap, nullptr, h_ap_bf, NA + NP, 256, 256, 0, stream);
    gemm_bf(hp_bf,   w_gat_pp, nullptr, h_pp_bf, NP,      256, 256, 0, stream);

    // ---- el/er ----
    attn_lr_kernel<<<(40000 * 8 + 255) / 256, 256, 0, stream>>>(h_ap_bf, al_ap, ar_ap, el_ap, er_ap, 40000);
    attn_lr_kernel<<<(20000 * 8 + 255) / 256, 256, 0, stream>>>(h_pp_bf, al_pp, ar_pp, el_pp, er_pp, 20000);

    // ---- CSR build ----
    zero_ints_kernel<<<(40000 + 255) / 256, 256, 0, stream>>>(ap_cur, 40000);
    count_deg_kernel<<<(E_AP_N + 255) / 256, 256, 0, stream>>>(ap_dst, ap_cur, E_AP_N);
    count_deg_kernel<<<(E_PP_N + 255) / 256, 256, 0, stream>>>(pp_dst, pp_cur, E_PP_N);
    exscan_kernel<<<1, 1024, 0, stream>>>(ap_cur, ap_offs, NP);
    exscan_kernel<<<1, 1024, 0, stream>>>(pp_cur, pp_offs, NP);
    zero_ints_kernel<<<(40000 + 255) / 256, 256, 0, stream>>>(ap_cur, 40000);
    scatter_kernel<<<(E_AP_N + 255) / 256, 256, 0, stream>>>(ap_src, ap_dst, ap_offs, ap_cur, ap_list, E_AP_N);
    scatter_kernel<<<(E_PP_N + 255) / 256, 256, 0, stream>>>(pp_src, pp_dst, pp_offs, pp_cur, pp_list, E_PP_N);

    // ---- GAT aggregation -> tgt slots 1,2 ----
    gat_agg_kernel<<<NP, 64, 0, stream>>>(h_ap_bf, el_ap, er_ap, ap_offs, ap_list, b_gat_ap, tgt_bf, NP, NA, 256);
    gat_agg_kernel<<<NP, 64, 0, stream>>>(h_pp_bf, el_pp, er_pp, pp_offs, pp_list, b_gat_pp, tgt_bf, NP, 0, 512);

    // ---- self attention: 2 chunks of 30000 rows (10000 papers) ----
    {
        ushort* qkv  = (ushort*)BIG;                    // 46.08 MB
        ushort* obuf = (ushort*)(BIG + 46080000);       // 15.36 MB
        ushort* proj = (ushort*)(BIG + 61440000);       // 15.36 MB
        for (int c = 0; c < 2; ++c) {
            size_t ro = (size_t)c * 30000 * 256;
            gemm_bf(tgt_bf + ro, w_qkv_s, bqkv_s, qkv, 30000, 768, 256, 0, stream);
            mha3_kernel<<<(10000 * 24 + 255) / 256, 256, 0, stream>>>(qkv, 768, 0, qkv, 768, 256, 512, obuf, 10000);
            gemm_bf(obuf, w_o_s, bo_s, proj, 30000, 256, 256, 0, stream);
            add_ln_kernel<<<30000 / 4, 256, 0, stream>>>(tgt_bf + ro, proj, ln1_g, ln1_b, X_bf + ro, 30000);
        }
    }

    // ---- cross attention: 2 chunks of 30000 rows ----
    {
        ushort* qb   = (ushort*)BIG;                    // 15.36 MB
        ushort* kvb  = (ushort*)(BIG + 15360000);       // 30.72 MB
        ushort* obuf = (ushort*)(BIG + 46080000);       // 15.36 MB
        ushort* proj = (ushort*)(BIG + 61440000);       // 15.36 MB
        for (int c = 0; c < 2; ++c) {
            size_t ro = (size_t)c * 30000 * 256;
            gemm_bf(X_bf + ro,   w_qkv_c,              bqkv_c,       qb,  30000, 256, 256, 0, stream);
            gemm_bf(tgt_bf + ro, w_qkv_c + 256 * 256,  bqkv_c + 256, kvb, 30000, 512, 256, 0, stream);
            mha3_kernel<<<(10000 * 24 + 255) / 256, 256, 0, stream>>>(qb, 256, 0, kvb, 512, 0, 256, obuf, 10000);
            gemm_bf(obuf, w_o_c, bo_c, proj, 30000, 256, 256, 0, stream);
            add_ln_kernel<<<30000 / 4, 256, 0, stream>>>(X_bf + ro, proj, ln2_g, ln2_b, X_bf + ro, 30000);
        }
    }

    // ---- feed-forward: 3 chunks of 20000 rows ----
    {
        ushort* ff1o = (ushort*)BIG;                    // 81.92 MB
        ushort* ff2o = (ushort*)(BIG + 81920000);       // 10.24 MB
        for (int c = 0; c < 3; ++c) {
            size_t ro = (size_t)c * 20000 * 256;
            gemm_bf(X_bf + ro, w_ff1, b_ff1, ff1o, 20000, 2048, 256, 2, stream);  // relu
            gemm_bf(ff1o, w_ff2, b_ff2, ff2o, 20000, 256, 2048, 0, stream);
            add_ln_kernel<<<20000 / 4, 256, 0, stream>>>(X_bf + ro, ff2o, ln3_g, ln3_b, X_bf + ro, 20000);
        }
    }

    // ---- prediction head: X viewed as (20000,768) @ W_pred^T -> f32 d_out ----
    gemm_bf(X_bf, w_pred, b_pred, (float*)d_out, NP, 64, 768, 1, stream);
}

// Round 4
// 1283.246 us; speedup vs baseline: 4.7738x; 1.1161x over previous
//
#include <hip/hip_runtime.h>
#include <hip/hip_bf16.h>
#include <cstdint>
#include <cstddef>

#define NP_N 20000
#define NA_N 20000
#define E_AP_N 400000
#define E_PP_N 400000
// D_IN=128, D_H=256, HEADS=8, D_HEAD=32, D_FF=2048, D_OUT=64

typedef __attribute__((ext_vector_type(8))) short bf16x8;
typedef __attribute__((ext_vector_type(4))) float f32x4;

__device__ __forceinline__ float b2f(ushort u) { return __uint_as_float(((uint32_t)u) << 16); }
__device__ __forceinline__ ushort f2b(float f) {
    uint32_t x = __float_as_uint(f);
    return (ushort)((x + 0x7fffu + ((x >> 16) & 1u)) >> 16);  // RNE (no NaN inputs here)
}

// ---------------------------------------------------------------------------
// f32 -> bf16 convert (n multiple of 4)
// ---------------------------------------------------------------------------
__global__ void cvt_kernel(const float* __restrict__ in, ushort* __restrict__ out, int n4)
{
    int i = blockIdx.x * blockDim.x + threadIdx.x;
    if (i >= n4) return;
    float4 v = ((const float4*)in)[i];
    ushort4 o;
    o.x = f2b(v.x); o.y = f2b(v.y); o.z = f2b(v.z); o.w = f2b(v.w);
    ((ushort4*)out)[i] = o;
}

// ---------------------------------------------------------------------------
// bf16 MFMA GEMM: C(N,M) = A(N,K) @ B(M,K)^T + bias.
// 128x128 tile, BK=32, 256 threads (4 waves, 2x2), 4x4 16x16 frags per wave.
// DOUBLE-BUFFERED K-loop: stage tile t+1 while computing tile t; one
// __syncthreads per iter (its vmcnt(0)+barrier drains the prefetch).
// OUT_MODE: 0 = bf16, 1 = f32, 2 = bf16 + relu
// ---------------------------------------------------------------------------
template <int OUT_MODE>
__global__ __launch_bounds__(256) void gemm_mfma(
    const ushort* __restrict__ A, const ushort* __restrict__ B,
    const float* __restrict__ bias, void* __restrict__ Cv,
    int N, int M, int K)
{
    __shared__ __align__(16) ushort Abuf[2][4][128 * 8];
    __shared__ __align__(16) ushort Bbuf[2][4][128 * 8];
    const int tid = threadIdx.x;
    const int lane = tid & 63;
    const int w = tid >> 6;
    const int wr = w >> 1, wc = w & 1;
    const int row0 = blockIdx.x * 128;
    const int col0 = blockIdx.y * 128;
    f32x4 acc[4][4] = {};

    auto stage = [&](int buf, int k0) {
#pragma unroll
        for (int i = 0; i < 4; ++i) {
            int c = w * 4 + i;
            int ks = c & 3;
            int rowhalf = (c >> 2) & 1;
            int r = rowhalf * 64 + lane;
            const ushort* src;
            ushort* dst;
            if (c < 8) {
                int gr = row0 + r; if (gr > N - 1) gr = N - 1;
                src = A + (size_t)gr * K + k0 + ks * 8;
                dst = &Abuf[buf][ks][rowhalf * 64 * 8];
            } else {
                int gc = col0 + r; if (gc > M - 1) gc = M - 1;
                src = B + (size_t)gc * K + k0 + ks * 8;
                dst = &Bbuf[buf][ks][rowhalf * 64 * 8];
            }
            __builtin_amdgcn_global_load_lds(
                (const __attribute__((address_space(1))) void*)src,
                (__attribute__((address_space(3))) void*)dst, 16, 0, 0);
        }
    };

    const int nk = K >> 5;
    stage(0, 0);
    __syncthreads();

    for (int t = 0; t < nk; ++t) {
        const int cur = t & 1;
        if (t + 1 < nk) stage(cur ^ 1, (t + 1) << 5);

        bf16x8 af[4], bfr[4];
        const int ks = lane >> 4;
        const int rl = lane & 15;
#pragma unroll
        for (int m = 0; m < 4; ++m)
            af[m] = *(const bf16x8*)&Abuf[cur][ks][(wr * 64 + m * 16 + rl) * 8];
#pragma unroll
        for (int n = 0; n < 4; ++n)
            bfr[n] = *(const bf16x8*)&Bbuf[cur][ks][(wc * 64 + n * 16 + rl) * 8];
#pragma unroll
        for (int m = 0; m < 4; ++m)
#pragma unroll
            for (int n = 0; n < 4; ++n)
                acc[m][n] = __builtin_amdgcn_mfma_f32_16x16x32_bf16(af[m], bfr[n], acc[m][n], 0, 0, 0);
        __syncthreads();
    }

    // epilogue: C/D layout col=lane&15, row=(lane>>4)*4+reg
#pragma unroll
    for (int m = 0; m < 4; ++m) {
#pragma unroll
        for (int n = 0; n < 4; ++n) {
            int gc = col0 + wc * 64 + n * 16 + (lane & 15);
            if (gc >= M) continue;
            float bv = bias ? bias[gc] : 0.f;
#pragma unroll
            for (int r = 0; r < 4; ++r) {
                int grow = row0 + wr * 64 + m * 16 + (lane >> 4) * 4 + r;
                if (grow >= N) continue;
                float v = acc[m][n][r] + bv;
                if (OUT_MODE == 2) v = fmaxf(v, 0.f);
                if (OUT_MODE == 1) ((float*)Cv)[(size_t)grow * M + gc] = v;
                else ((ushort*)Cv)[(size_t)grow * M + gc] = f2b(v);
            }
        }
    }
}

static inline void gemm_bf(const ushort* A, const ushort* B, const float* bias, void* C,
                           int N, int M, int K, int mode, hipStream_t s)
{
    dim3 g((N + 127) / 128, (M + 127) / 128);
    if (mode == 0)      gemm_mfma<0><<<g, 256, 0, s>>>(A, B, bias, C, N, M, K);
    else if (mode == 1) gemm_mfma<1><<<g, 256, 0, s>>>(A, B, bias, C, N, M, K);
    else                gemm_mfma<2><<<g, 256, 0, s>>>(A, B, bias, C, N, M, K);
}

// ---------------------------------------------------------------------------
// Fused FF: ffout = relu(X @ W1^T + b1) @ W2^T + b2
// X:(N,256) bf16, W1:(2048,256), W2:(256,2048), ffout:(N,256) bf16.
// Block = 64 rows x 256 cols, 256 threads (4 waves 2x2).
// Loop 32 f-chunks of 64: phase A S=relu(X@W1c^T+b1) -> LDS bf16;
// phase B O += S@W2c^T (persistent 2x8 f32x4 acc).
// X fragments live in registers (loaded once). W1/W2 staged via
// global_load_lds (L2-resident weights).
// ---------------------------------------------------------------------------
__global__ __launch_bounds__(256, 2) void ff_fused_kernel(
    const ushort* __restrict__ X, const ushort* __restrict__ W1,
    const ushort* __restrict__ W2, const float* __restrict__ b1,
    const float* __restrict__ b2, ushort* __restrict__ ffout, int N)
{
    __shared__ __align__(16) ushort W1buf[32 * 64 * 8];   // [s=k/8][frow][8]  32 KB
    __shared__ __align__(16) ushort W2buf[8 * 256 * 8];   // [s=f/8][c][8]     32 KB
    __shared__ __align__(16) ushort Sbuf[8 * 64 * 8];     // [s=f/8][row][8]    8 KB
    const int tid = threadIdx.x;
    const int lane = tid & 63;
    const int w = tid >> 6;
    const int wr = w >> 1, wc = w & 1;
    const int row0 = blockIdx.x * 64;
    const int rl = lane & 15;
    const int ks = lane >> 4;

    // persistent X fragments: xf[m][kc] rows wr*32+m*16+rl, k = ks*8 + kc*32
    bf16x8 xf[2][8];
#pragma unroll
    for (int m = 0; m < 2; ++m) {
        int gr = row0 + wr * 32 + m * 16 + rl;
        if (gr > N - 1) gr = N - 1;
        const ushort* xrow = X + (size_t)gr * 256 + ks * 8;
#pragma unroll
        for (int kc = 0; kc < 8; ++kc)
            xf[m][kc] = *(const bf16x8*)(xrow + kc * 32);
    }

    f32x4 oacc[2][8] = {};

    for (int fc = 0; fc < 32; ++fc) {
        const int f0 = fc * 64;
        // ---- stage W1 chunk (64x256) and W2 chunk (256x64) ----
#pragma unroll
        for (int i = 0; i < 8; ++i) {
            int ii = w * 8 + i;
            const ushort* s1 = W1 + (size_t)(f0 + lane) * 256 + ii * 8;
            __builtin_amdgcn_global_load_lds(
                (const __attribute__((address_space(1))) void*)s1,
                (__attribute__((address_space(3))) void*)&W1buf[ii * 64 * 8], 16, 0, 0);
            const ushort* s2 = W2 + (size_t)((ii & 3) * 64 + lane) * 2048 + f0 + (ii >> 2) * 8;
            __builtin_amdgcn_global_load_lds(
                (const __attribute__((address_space(1))) void*)s2,
                (__attribute__((address_space(3))) void*)&W2buf[(ii >> 2) * 2048 + ((ii & 3) * 64) * 8], 16, 0, 0);
        }
        __syncthreads();  // vmcnt(0) drain + barrier: stage visible

        // ---- phase A: S = relu(X @ W1c^T + b1), 64x64 ----
        f32x4 sacc[2][2] = {};
#pragma unroll
        for (int kc = 0; kc < 8; ++kc) {
            bf16x8 w1f[2];
#pragma unroll
            for (int n = 0; n < 2; ++n)
                w1f[n] = *(const bf16x8*)&W1buf[((kc * 4 + ks) * 64 + wc * 32 + n * 16 + rl) * 8];
#pragma unroll
            for (int m = 0; m < 2; ++m)
#pragma unroll
                for (int n = 0; n < 2; ++n)
                    sacc[m][n] = __builtin_amdgcn_mfma_f32_16x16x32_bf16(xf[m][kc], w1f[n], sacc[m][n], 0, 0, 0);
        }
#pragma unroll
        for (int m = 0; m < 2; ++m)
#pragma unroll
            for (int n = 0; n < 2; ++n) {
                int fl = wc * 32 + n * 16 + rl;
                float bv = b1[f0 + fl];
                int rbase = wr * 32 + m * 16 + ks * 4;
#pragma unroll
                for (int r = 0; r < 4; ++r) {
                    float v = fmaxf(sacc[m][n][r] + bv, 0.f);
                    Sbuf[(fl >> 3) * 512 + (rbase + r) * 8 + (fl & 7)] = f2b(v);
                }
            }
        __syncthreads();  // S visible (also: all W1buf reads complete)

        // ---- phase B: O += S @ W2c^T ----
#pragma unroll
        for (int kc = 0; kc < 2; ++kc) {
            bf16x8 sf[2], w2f[8];
#pragma unroll
            for (int m = 0; m < 2; ++m)
                sf[m] = *(const bf16x8*)&Sbuf[((kc * 4 + ks) * 64 + wr * 32 + m * 16 + rl) * 8];
#pragma unroll
            for (int n = 0; n < 8; ++n)
                w2f[n] = *(const bf16x8*)&W2buf[(kc * 4 + ks) * 2048 + (wc * 128 + n * 16 + rl) * 8];
#pragma unroll
            for (int m = 0; m < 2; ++m)
#pragma unroll
                for (int n = 0; n < 8; ++n)
                    oacc[m][n] = __builtin_amdgcn_mfma_f32_16x16x32_bf16(sf[m], w2f[n], oacc[m][n], 0, 0, 0);
        }
        __syncthreads();  // phase-B reads done before next chunk's staging
    }

    // ---- epilogue: ffout = O + b2 ----
#pragma unroll
    for (int n = 0; n < 8; ++n) {
        int c = wc * 128 + n * 16 + rl;
        float bv = b2[c];
#pragma unroll
        for (int m = 0; m < 2; ++m) {
            int rbase = row0 + wr * 32 + m * 16 + ks * 4;
#pragma unroll
            for (int r = 0; r < 4; ++r) {
                int gr = rbase + r;
                if (gr < N) ffout[(size_t)gr * 256 + c] = f2b(oacc[m][n][r] + bv);
            }
        }
    }
}

// ---------------------------------------------------------------------------
// copy hp(bf16) -> tgt[:,0,:]  (tgt row stride 768), ushort4 per thread
// ---------------------------------------------------------------------------
__global__ void copy_col0_kernel(const ushort* __restrict__ src, ushort* __restrict__ tgt, int n)
{
    int i = blockIdx.x * blockDim.x + threadIdx.x;
    if (i >= n) return;  // n = NP*64
    int p = i >> 6, c = i & 63;
    ((ushort4*)tgt)[(size_t)p * 192 + c] = ((const ushort4*)src)[(size_t)p * 64 + c];
}

__global__ void zero_ints_kernel(int* __restrict__ p, int n)
{
    int i = blockIdx.x * blockDim.x + threadIdx.x;
    if (i < n) p[i] = 0;
}

// ---------------------------------------------------------------------------
// GAT el/er projections from bf16 h
// ---------------------------------------------------------------------------
__global__ void attn_lr_kernel(const ushort* __restrict__ h, const float* __restrict__ al,
                               const float* __restrict__ ar, float* __restrict__ el,
                               float* __restrict__ er, int N)
{
    int idx = blockIdx.x * blockDim.x + threadIdx.x;
    if (idx >= N * 8) return;
    int hd = idx & 7;
    const ushort* hp = h + (size_t)(idx >> 3) * 256 + hd * 32;
    const float* a1 = al + hd * 32;
    const float* a2 = ar + hd * 32;
    float s1 = 0.f, s2 = 0.f;
#pragma unroll
    for (int j = 0; j < 8; ++j) {
        ushort4 t = ((const ushort4*)hp)[j];
        float v0 = b2f(t.x), v1 = b2f(t.y), v2 = b2f(t.z), v3 = b2f(t.w);
        s1 = fmaf(v0, a1[j * 4 + 0], s1); s2 = fmaf(v0, a2[j * 4 + 0], s2);
        s1 = fmaf(v1, a1[j * 4 + 1], s1); s2 = fmaf(v1, a2[j * 4 + 1], s2);
        s1 = fmaf(v2, a1[j * 4 + 2], s1); s2 = fmaf(v2, a2[j * 4 + 2], s2);
        s1 = fmaf(v3, a1[j * 4 + 3], s1); s2 = fmaf(v3, a2[j * 4 + 3], s2);
    }
    el[idx] = s1;
    er[idx] = s2;
}

// ---------------------------------------------------------------------------
// CSR build
// ---------------------------------------------------------------------------
__global__ void count_deg_kernel(const int* __restrict__ dst, int* __restrict__ deg, int E)
{
    int e = blockIdx.x * blockDim.x + threadIdx.x;
    if (e < E) atomicAdd(&deg[dst[e]], 1);
}

__global__ void exscan_kernel(const int* __restrict__ deg, int* __restrict__ offs, int N)
{
    __shared__ int sbuf[1024];
    __shared__ int carry;
    int tid = threadIdx.x;
    if (tid == 0) carry = 0;
    __syncthreads();
    for (int base = 0; base < N; base += 1024) {
        int i = base + tid;
        int v = (i < N) ? deg[i] : 0;
        sbuf[tid] = v;
        __syncthreads();
        for (int off = 1; off < 1024; off <<= 1) {
            int t = (tid >= off) ? sbuf[tid - off] : 0;
            __syncthreads();
            sbuf[tid] += t;
            __syncthreads();
        }
        if (i < N) offs[i] = carry + sbuf[tid] - v;
        int chunk_total = sbuf[1023];
        __syncthreads();
        if (tid == 0) carry += chunk_total;
        __syncthreads();
    }
    if (tid == 0) offs[N] = carry;
}

__global__ void scatter_kernel(const int* __restrict__ src, const int* __restrict__ dst,
                               const int* __restrict__ offs, int* __restrict__ cur,
                               int* __restrict__ elist, int E)
{
    int e = blockIdx.x * blockDim.x + threadIdx.x;
    if (e >= E) return;
    int d = dst[e];
    int pos = atomicAdd(&cur[d], 1);
    elist[offs[d] + pos] = src[e];
}

// ---------------------------------------------------------------------------
// GAT aggregation: one wave per dst paper; lane owns 4 consecutive cols,
// so head = lane>>3 is uniform per lane -> one exp per edge per lane.
// ---------------------------------------------------------------------------
__global__ __launch_bounds__(64) void gat_agg_kernel(
    const ushort* __restrict__ h, const float* __restrict__ el, const float* __restrict__ er,
    const int* __restrict__ offs, const int* __restrict__ elist,
    const float* __restrict__ bias, ushort* __restrict__ out,
    int Ndst, int self_base, int out_coloff)
{
    int p = blockIdx.x;
    if (p >= Ndst) return;
    int l = threadIdx.x;
    int head = l >> 3;
    int dn = self_base + p;
    float erv = er[(size_t)dn * 8 + head];
    float acc[4] = {0.f, 0.f, 0.f, 0.f};
    float z = 0.f;
    int beg = offs[p], end = offs[p + 1];
    for (int e = beg - 1; e < end; ++e) {
        int s = (e < beg) ? dn : elist[e];
        float x = el[(size_t)s * 8 + head] + erv;
        x = x > 0.f ? x : 0.2f * x;
        float wgt = expf(x);
        z += wgt;
        ushort4 hv = *(const ushort4*)&h[(size_t)s * 256 + l * 4];
        acc[0] = fmaf(wgt, b2f(hv.x), acc[0]);
        acc[1] = fmaf(wgt, b2f(hv.y), acc[1]);
        acc[2] = fmaf(wgt, b2f(hv.z), acc[2]);
        acc[3] = fmaf(wgt, b2f(hv.w), acc[3]);
    }
    float inv = 1.f / z;
    ushort4 o;
    o.x = f2b(acc[0] * inv + bias[l * 4 + 0]);
    o.y = f2b(acc[1] * inv + bias[l * 4 + 1]);
    o.z = f2b(acc[2] * inv + bias[l * 4 + 2]);
    o.w = f2b(acc[3] * inv + bias[l * 4 + 3]);
    *(ushort4*)&out[(size_t)p * 768 + out_coloff + l * 4] = o;
}

// ---------------------------------------------------------------------------
// Tiny MHA (S=Sk=3): one thread per (paper, query, head); bf16 in/out.
// ---------------------------------------------------------------------------
__global__ void mha3_kernel(const ushort* __restrict__ qb, int ldq, int qoff,
                            const ushort* __restrict__ kvb, int ldkv, int koff, int voff,
                            ushort* __restrict__ ob, int NPn)
{
    int idx = blockIdx.x * blockDim.x + threadIdx.x;
    if (idx >= NPn * 24) return;
    int h = idx & 7;
    int i = (idx >> 3) % 3;
    int p = idx / 24;
    float qr[32];
    {
        const ushort* q = qb + (size_t)(p * 3 + i) * ldq + qoff + h * 32;
#pragma unroll
        for (int j = 0; j < 8; ++j) {
            ushort4 t = ((const ushort4*)q)[j];
            qr[j * 4 + 0] = b2f(t.x); qr[j * 4 + 1] = b2f(t.y);
            qr[j * 4 + 2] = b2f(t.z); qr[j * 4 + 3] = b2f(t.w);
        }
    }
    float s[3];
#pragma unroll
    for (int j = 0; j < 3; ++j) {
        const ushort* k = kvb + (size_t)(p * 3 + j) * ldkv + koff + h * 32;
        float a = 0.f;
#pragma unroll
        for (int t4 = 0; t4 < 8; ++t4) {
            ushort4 t = ((const ushort4*)k)[t4];
            a = fmaf(qr[t4 * 4 + 0], b2f(t.x), a);
            a = fmaf(qr[t4 * 4 + 1], b2f(t.y), a);
            a = fmaf(qr[t4 * 4 + 2], b2f(t.z), a);
            a = fmaf(qr[t4 * 4 + 3], b2f(t.w), a);
        }
        s[j] = a * 0.17677669529663687f;
    }
    float m = fmaxf(s[0], fmaxf(s[1], s[2]));
    float e0 = expf(s[0] - m), e1 = expf(s[1] - m), e2 = expf(s[2] - m);
    float inv = 1.f / (e0 + e1 + e2);
    float aw[3] = {e0 * inv, e1 * inv, e2 * inv};
    float o[32] = {};
#pragma unroll
    for (int j = 0; j < 3; ++j) {
        const ushort* v = kvb + (size_t)(p * 3 + j) * ldkv + voff + h * 32;
#pragma unroll
        for (int t4 = 0; t4 < 8; ++t4) {
            ushort4 t = ((const ushort4*)v)[t4];
            o[t4 * 4 + 0] = fmaf(aw[j], b2f(t.x), o[t4 * 4 + 0]);
            o[t4 * 4 + 1] = fmaf(aw[j], b2f(t.y), o[t4 * 4 + 1]);
            o[t4 * 4 + 2] = fmaf(aw[j], b2f(t.z), o[t4 * 4 + 2]);
            o[t4 * 4 + 3] = fmaf(aw[j], b2f(t.w), o[t4 * 4 + 3]);
        }
    }
    ushort* op = ob + (size_t)(p * 3 + i) * 256 + h * 32;
#pragma unroll
    for (int t4 = 0; t4 < 8; ++t4) {
        ushort4 t;
        t.x = f2b(o[t4 * 4 + 0]); t.y = f2b(o[t4 * 4 + 1]);
        t.z = f2b(o[t4 * 4 + 2]); t.w = f2b(o[t4 * 4 + 3]);
        ((ushort4*)op)[t4] = t;
    }
}

// ---------------------------------------------------------------------------
// Fused residual add + LayerNorm (256 ch), bf16 in/out, wave per row.
// ---------------------------------------------------------------------------
__global__ __launch_bounds__(256) void add_ln_kernel(
    const ushort* __restrict__ a, const ushort* __restrict__ b,
    const float* __restrict__ g, const float* __restrict__ be,
    ushort* __restrict__ out, int rows)
{
    int row = blockIdx.x * 4 + (threadIdx.x >> 6);
    if (row >= rows) return;
    int l = threadIdx.x & 63;
    ushort4 va = *(const ushort4*)&a[(size_t)row * 256 + l * 4];
    ushort4 vb = *(const ushort4*)&b[(size_t)row * 256 + l * 4];
    float v[4];
    v[0] = b2f(va.x) + b2f(vb.x);
    v[1] = b2f(va.y) + b2f(vb.y);
    v[2] = b2f(va.z) + b2f(vb.z);
    v[3] = b2f(va.w) + b2f(vb.w);
    float s = v[0] + v[1] + v[2] + v[3];
#pragma unroll
    for (int off = 32; off; off >>= 1) s += __shfl_xor(s, off);
    float mean = s * (1.f / 256.f);
    float s2 = 0.f;
#pragma unroll
    for (int j = 0; j < 4; ++j) { float d = v[j] - mean; s2 = fmaf(d, d, s2); }
#pragma unroll
    for (int off = 32; off; off >>= 1) s2 += __shfl_xor(s2, off);
    float rstd = rsqrtf(s2 * (1.f / 256.f) + 1e-5f);
    ushort4 o;
    o.x = f2b((v[0] - mean) * rstd * g[l * 4 + 0] + be[l * 4 + 0]);
    o.y = f2b((v[1] - mean) * rstd * g[l * 4 + 1] + be[l * 4 + 1]);
    o.z = f2b((v[2] - mean) * rstd * g[l * 4 + 2] + be[l * 4 + 2]);
    o.w = f2b((v[3] - mean) * rstd * g[l * 4 + 3] + be[l * 4 + 3]);
    *(ushort4*)&out[(size_t)row * 256 + l * 4] = o;
}

// ---------------------------------------------------------------------------
// kernel_launch — ws budget 184.32 MB (proven safe).
// [0, 30.72M)     tgt_bf (60000x256 bf16)
// [30.72, 61.44M) X_bf
// [61.44, 65.08M) weights bf16
// [65.08, 184.32M) BIG (119.24 MB), era-overlaid
// ---------------------------------------------------------------------------
extern "C" void kernel_launch(void* const* d_in, const int* in_sizes, int n_in,
                              void* d_out, int out_size, void* d_ws, size_t ws_size,
                              hipStream_t stream)
{
    const float* feat_paper  = (const float*)d_in[0];
    const float* feat_author = (const float*)d_in[1];
    const float* W_in_p  = (const float*)d_in[2];
    const float* b_in_p  = (const float*)d_in[3];
    const float* W_in_a  = (const float*)d_in[4];
    const float* b_in_a  = (const float*)d_in[5];
    const float* W_gat_ap = (const float*)d_in[6];
    const float* al_ap    = (const float*)d_in[7];
    const float* ar_ap    = (const float*)d_in[8];
    const float* b_gat_ap = (const float*)d_in[9];
    const float* W_gat_pp = (const float*)d_in[10];
    const float* al_pp    = (const float*)d_in[11];
    const float* ar_pp    = (const float*)d_in[12];
    const float* b_gat_pp = (const float*)d_in[13];
    const float* Wqkv_s = (const float*)d_in[14];
    const float* bqkv_s = (const float*)d_in[15];
    const float* Wo_s   = (const float*)d_in[16];
    const float* bo_s   = (const float*)d_in[17];
    const float* Wqkv_c = (const float*)d_in[18];
    const float* bqkv_c = (const float*)d_in[19];
    const float* Wo_c   = (const float*)d_in[20];
    const float* bo_c   = (const float*)d_in[21];
    const float* W_ff1  = (const float*)d_in[22];
    const float* b_ff1  = (const float*)d_in[23];
    const float* W_ff2  = (const float*)d_in[24];
    const float* b_ff2  = (const float*)d_in[25];
    const float* ln1_g  = (const float*)d_in[26];
    const float* ln1_b  = (const float*)d_in[27];
    const float* ln2_g  = (const float*)d_in[28];
    const float* ln2_b  = (const float*)d_in[29];
    const float* ln3_g  = (const float*)d_in[30];
    const float* ln3_b  = (const float*)d_in[31];
    const float* W_pred = (const float*)d_in[32];
    const float* b_pred = (const float*)d_in[33];
    const int* ap_src = (const int*)d_in[34];
    const int* ap_dst = (const int*)d_in[35];
    const int* pp_src = (const int*)d_in[36];
    const int* pp_dst = (const int*)d_in[37];

    const int NP = NP_N, NA = NA_N;

    uint8_t* wsb = (uint8_t*)d_ws;
    ushort* tgt_bf = (ushort*)wsb;
    ushort* X_bf   = (ushort*)(wsb + 30720000);
    ushort* WB     = (ushort*)(wsb + 61440000);
    // weight offsets (elems)
    ushort* w_in_p  = WB + 0;
    ushort* w_in_a  = WB + 32768;
    ushort* w_gat_ap = WB + 65536;
    ushort* w_gat_pp = WB + 131072;
    ushort* w_qkv_s = WB + 196608;
    ushort* w_o_s   = WB + 393216;
    ushort* w_qkv_c = WB + 458752;
    ushort* w_o_c   = WB + 655360;
    ushort* w_ff1   = WB + 720896;
    ushort* w_ff2   = WB + 1245184;
    ushort* w_pred  = WB + 1769472;
    uint8_t* BIG = wsb + 65080000;

    auto cvt = [&](const float* in, ushort* out, int n) {
        int n4 = n / 4;
        cvt_kernel<<<(n4 + 255) / 256, 256, 0, stream>>>(in, out, n4);
    };
    // era A overlay inside BIG
    ushort* feat_p_bf = (ushort*)BIG;
    ushort* feat_a_bf = (ushort*)(BIG + 5120000);
    ushort* x_ap_bf   = (ushort*)(BIG + 10240000);
    ushort* hp_bf     = x_ap_bf + (size_t)NA * 256;
    ushort* h_ap_bf   = (ushort*)(BIG + 30720000);
    ushort* h_pp_bf   = (ushort*)(BIG + 51200000);
    float* el_ap = (float*)(BIG + 61440000);
    float* er_ap = (float*)(BIG + 62720000);
    float* el_pp = (float*)(BIG + 64000000);
    float* er_pp = (float*)(BIG + 64640000);
    int* ireg    = (int*)(BIG + 65280000);
    int* ap_offs = ireg;
    int* pp_offs = ireg + 20001;
    int* ap_cur  = ireg + 40002;
    int* pp_cur  = ireg + 60002;
    int* ap_list = ireg + 80002;
    int* pp_list = ireg + 480002;

    cvt(feat_paper,  feat_p_bf, NP * 128);
    cvt(feat_author, feat_a_bf, NA * 128);
    cvt(W_in_p, w_in_p, 32768);
    cvt(W_in_a, w_in_a, 32768);
    cvt(W_gat_ap, w_gat_ap, 65536);
    cvt(W_gat_pp, w_gat_pp, 65536);
    cvt(Wqkv_s, w_qkv_s, 196608);
    cvt(Wo_s, w_o_s, 65536);
    cvt(Wqkv_c, w_qkv_c, 196608);
    cvt(Wo_c, w_o_c, 65536);
    cvt(W_ff1, w_ff1, 524288);
    cvt(W_ff2, w_ff2, 524288);
    cvt(W_pred, w_pred, 49152);

    // ---- input projections (bf16 out) ----
    gemm_bf(feat_a_bf, w_in_a, b_in_a, x_ap_bf, NA, 256, 128, 0, stream);
    gemm_bf(feat_p_bf, w_in_p, b_in_p, hp_bf,   NP, 256, 128, 0, stream);

    // tgt[:,0,:] = hp
    copy_col0_kernel<<<(NP * 64 + 255) / 256, 256, 0, stream>>>(hp_bf, tgt_bf, NP * 64);

    // ---- GAT feature transforms (no bias) ----
    gemm_bf(x_ap_bf, w_gat_ap, nullptr, h_ap_bf, NA + NP, 256, 256, 0, stream);
    gemm_bf(hp_bf,   w_gat_pp, nullptr, h_pp_bf, NP,      256, 256, 0, stream);

    // ---- el/er ----
    attn_lr_kernel<<<(40000 * 8 + 255) / 256, 256, 0, stream>>>(h_ap_bf, al_ap, ar_ap, el_ap, er_ap, 40000);
    attn_lr_kernel<<<(20000 * 8 + 255) / 256, 256, 0, stream>>>(h_pp_bf, al_pp, ar_pp, el_pp, er_pp, 20000);

    // ---- CSR build ----
    zero_ints_kernel<<<(40000 + 255) / 256, 256, 0, stream>>>(ap_cur, 40000);
    count_deg_kernel<<<(E_AP_N + 255) / 256, 256, 0, stream>>>(ap_dst, ap_cur, E_AP_N);
    count_deg_kernel<<<(E_PP_N + 255) / 256, 256, 0, stream>>>(pp_dst, pp_cur, E_PP_N);
    exscan_kernel<<<1, 1024, 0, stream>>>(ap_cur, ap_offs, NP);
    exscan_kernel<<<1, 1024, 0, stream>>>(pp_cur, pp_offs, NP);
    zero_ints_kernel<<<(40000 + 255) / 256, 256, 0, stream>>>(ap_cur, 40000);
    scatter_kernel<<<(E_AP_N + 255) / 256, 256, 0, stream>>>(ap_src, ap_dst, ap_offs, ap_cur, ap_list, E_AP_N);
    scatter_kernel<<<(E_PP_N + 255) / 256, 256, 0, stream>>>(pp_src, pp_dst, pp_offs, pp_cur, pp_list, E_PP_N);

    // ---- GAT aggregation -> tgt slots 1,2 ----
    gat_agg_kernel<<<NP, 64, 0, stream>>>(h_ap_bf, el_ap, er_ap, ap_offs, ap_list, b_gat_ap, tgt_bf, NP, NA, 256);
    gat_agg_kernel<<<NP, 64, 0, stream>>>(h_pp_bf, el_pp, er_pp, pp_offs, pp_list, b_gat_pp, tgt_bf, NP, 0, 512);

    // ---- self attention: 2 chunks of 30000 rows (10000 papers) ----
    {
        ushort* qkv  = (ushort*)BIG;
        ushort* obuf = (ushort*)(BIG + 46080000);
        ushort* proj = (ushort*)(BIG + 61440000);
        for (int c = 0; c < 2; ++c) {
            size_t ro = (size_t)c * 30000 * 256;
            gemm_bf(tgt_bf + ro, w_qkv_s, bqkv_s, qkv, 30000, 768, 256, 0, stream);
            mha3_kernel<<<(10000 * 24 + 255) / 256, 256, 0, stream>>>(qkv, 768, 0, qkv, 768, 256, 512, obuf, 10000);
            gemm_bf(obuf, w_o_s, bo_s, proj, 30000, 256, 256, 0, stream);
            add_ln_kernel<<<30000 / 4, 256, 0, stream>>>(tgt_bf + ro, proj, ln1_g, ln1_b, X_bf + ro, 30000);
        }
    }

    // ---- cross attention: 2 chunks of 30000 rows ----
    {
        ushort* qb   = (ushort*)BIG;
        ushort* kvb  = (ushort*)(BIG + 15360000);
        ushort* obuf = (ushort*)(BIG + 46080000);
        ushort* proj = (ushort*)(BIG + 61440000);
        for (int c = 0; c < 2; ++c) {
            size_t ro = (size_t)c * 30000 * 256;
            gemm_bf(X_bf + ro,   w_qkv_c,              bqkv_c,       qb,  30000, 256, 256, 0, stream);
            gemm_bf(tgt_bf + ro, w_qkv_c + 256 * 256,  bqkv_c + 256, kvb, 30000, 512, 256, 0, stream);
            mha3_kernel<<<(10000 * 24 + 255) / 256, 256, 0, stream>>>(qb, 256, 0, kvb, 512, 0, 256, obuf, 10000);
            gemm_bf(obuf, w_o_c, bo_c, proj, 30000, 256, 256, 0, stream);
            add_ln_kernel<<<30000 / 4, 256, 0, stream>>>(X_bf + ro, proj, ln2_g, ln2_b, X_bf + ro, 30000);
        }
    }

    // ---- feed-forward: single fused dispatch over all 60000 rows ----
    {
        ushort* ffo = (ushort*)BIG;   // 30.72 MB
        ff_fused_kernel<<<(60000 + 63) / 64, 256, 0, stream>>>(X_bf, w_ff1, w_ff2, b_ff1, b_ff2, ffo, 60000);
        add_ln_kernel<<<60000 / 4, 256, 0, stream>>>(X_bf, ffo, ln3_g, ln3_b, X_bf, 60000);
    }

    // ---- prediction head: X viewed as (20000,768) @ W_pred^T -> f32 d_out ----
    gemm_bf(X_bf, w_pred, b_pred, (float*)d_out, NP, 64, 768, 1, stream);
}

// Round 5
// 945.032 us; speedup vs baseline: 6.4822x; 1.3579x over previous
//
#include <hip/hip_runtime.h>
#include <hip/hip_bf16.h>
#include <cstdint>
#include <cstddef>

#define NP_N 20000
#define NA_N 20000
#define E_AP_N 400000
#define E_PP_N 400000
// D_IN=128, D_H=256, HEADS=8, D_HEAD=32, D_FF=2048, D_OUT=64

typedef __attribute__((ext_vector_type(8))) short bf16x8;
typedef __attribute__((ext_vector_type(4))) float f32x4;

__device__ __forceinline__ float b2f(ushort u) { return __uint_as_float(((uint32_t)u) << 16); }
__device__ __forceinline__ ushort f2b(float f) {
    uint32_t x = __float_as_uint(f);
    return (ushort)((x + 0x7fffu + ((x >> 16) & 1u)) >> 16);  // RNE (no NaN inputs here)
}

// ---------------------------------------------------------------------------
// f32 -> bf16 convert (row-order), n multiple of 4
// ---------------------------------------------------------------------------
__global__ void cvt_kernel(const float* __restrict__ in, ushort* __restrict__ out, int n4)
{
    int i = blockIdx.x * blockDim.x + threadIdx.x;
    if (i >= n4) return;
    float4 v = ((const float4*)in)[i];
    ushort4 o;
    o.x = f2b(v.x); o.y = f2b(v.y); o.z = f2b(v.z); o.w = f2b(v.w);
    ((ushort4*)out)[i] = o;
}

// ---------------------------------------------------------------------------
// Pack B(M,K) f32 row-major -> GEMM staging order:
// out[(j*KT + t)*4096 + ks*1024 + r*8 + e] = B[j*128+r][t*32+ks*8+e]  (bf16)
// zero-padded rows for j*128+r >= M. nquad = Mpad*K/4.
// ---------------------------------------------------------------------------
__global__ void packB_kernel(const float* __restrict__ B, ushort* __restrict__ out,
                             int M, int K, int nquad)
{
    int u = blockIdx.x * blockDim.x + threadIdx.x;
    if (u >= nquad) return;
    int KT = K >> 5;
    int q = u & 1023;
    int jt = u >> 10;
    int t = jt % KT, j = jt / KT;
    int ks = q >> 8, rem = q & 255;
    int r = rem >> 1;
    int e0 = (rem & 1) * 4;
    int row = j * 128 + r;
    int col = t * 32 + ks * 8 + e0;
    ushort4 o = {0, 0, 0, 0};
    if (row < M) {
        const float* s = B + (size_t)row * K + col;
        o.x = f2b(s[0]); o.y = f2b(s[1]); o.z = f2b(s[2]); o.w = f2b(s[3]);
    }
    ((ushort4*)out)[u] = o;
}

// ---------------------------------------------------------------------------
// FF weight packs: LDS-image order per 64-wide f-chunk.
// W1 (2048,256): out[chunk*16384 + s*512 + frow*8 + e] = W1[chunk*64+frow][s*8+e]
// W2 (256,2048): out[chunk*16384 + s2*2048 + c*8 + e] = W2[c][chunk*64+s2*8+e]
// ---------------------------------------------------------------------------
__global__ void packW1_kernel(const float* __restrict__ W1, ushort* __restrict__ out)
{
    int u = blockIdx.x * blockDim.x + threadIdx.x;  // 131072 quads
    if (u >= 131072) return;
    int q = u & 4095, chunk = u >> 12;
    int s = q >> 7, rem = q & 127;
    int frow = rem >> 1, e0 = (rem & 1) * 4;
    const float* src = W1 + (size_t)(chunk * 64 + frow) * 256 + s * 8 + e0;
    ushort4 o;
    o.x = f2b(src[0]); o.y = f2b(src[1]); o.z = f2b(src[2]); o.w = f2b(src[3]);
    ((ushort4*)out)[u] = o;
}

__global__ void packW2_kernel(const float* __restrict__ W2, ushort* __restrict__ out)
{
    int u = blockIdx.x * blockDim.x + threadIdx.x;  // 131072 quads
    if (u >= 131072) return;
    int q = u & 4095, chunk = u >> 12;
    int s2 = q >> 9, rem = q & 511;
    int c = rem >> 1, e0 = (rem & 1) * 4;
    const float* src = W2 + (size_t)c * 2048 + chunk * 64 + s2 * 8 + e0;
    ushort4 o;
    o.x = f2b(src[0]); o.y = f2b(src[1]); o.z = f2b(src[2]); o.w = f2b(src[3]);
    ((ushort4*)out)[u] = o;
}

// ---------------------------------------------------------------------------
// bf16 MFMA GEMM v2: C(N,M) = A(N,K) @ B(M,K)^T + bias.
// A: reg-staged (coalesced 16B loads along K, 4 lanes/line) + ds_write_b128.
// B: pre-packed staging order, contiguous global_load_lds.
// 128x128 tile, BK=32, double-buffered, ONE barrier per K-step.
// OUT_MODE: 0 = bf16, 1 = f32, 2 = bf16 + relu
// ---------------------------------------------------------------------------
template <int OUT_MODE>
__global__ __launch_bounds__(256) void gemm_mfma(
    const ushort* __restrict__ A, const ushort* __restrict__ Bp,
    const float* __restrict__ bias, void* __restrict__ Cv,
    int N, int M, int K)
{
    __shared__ __align__(16) ushort Ab[2][4][128 * 8];
    __shared__ __align__(16) ushort Bb[2][4][128 * 8];
    const int tid = threadIdx.x;
    const int lane = tid & 63;
    const int w = tid >> 6;
    const int wr = w >> 1, wc = w & 1;
    const int row0 = blockIdx.x * 128;
    const int col0 = blockIdx.y * 128;
    const int KT = K >> 5;
    const ushort* Bbase = Bp + (size_t)blockIdx.y * KT * 4096;
    f32x4 acc[4][4] = {};

    const int rsub = lane >> 2, ksl = lane & 3;
    int arow[2];
#pragma unroll
    for (int j = 0; j < 2; ++j) {
        int r = row0 + w * 32 + j * 16 + rsub;
        arow[j] = (r < N) ? r : (N - 1);
    }

    bf16x8 areg[2];
    auto loadA = [&](int k0) {
#pragma unroll
        for (int j = 0; j < 2; ++j)
            areg[j] = *(const bf16x8*)(A + (size_t)arow[j] * K + k0 + ksl * 8);
    };
    auto writeA = [&](int buf) {
#pragma unroll
        for (int j = 0; j < 2; ++j)
            *(bf16x8*)&Ab[buf][ksl][(w * 32 + j * 16 + rsub) * 8] = areg[j];
    };
    auto gloadB = [&](int buf, int t) {
#pragma unroll
        for (int i = 0; i < 2; ++i) {
            const ushort* src = Bbase + (size_t)t * 4096 + (w * 2 + i) * 512 + lane * 8;
            ushort* dst = (ushort*)Bb[buf] + (w * 2 + i) * 512;
            __builtin_amdgcn_global_load_lds(
                (const __attribute__((address_space(1))) void*)src,
                (__attribute__((address_space(3))) void*)dst, 16, 0, 0);
        }
    };

    loadA(0);
    gloadB(0, 0);
    writeA(0);          // waits on A reg loads only
    __syncthreads();    // drains B gload + A ds_write

    for (int t = 0; t < KT; ++t) {
        const int cur = t & 1;
        if (t + 1 < KT) { loadA((t + 1) << 5); gloadB(cur ^ 1, t + 1); }

        bf16x8 af[4], bfr[4];
        const int ks = lane >> 4;
        const int rl = lane & 15;
#pragma unroll
        for (int m = 0; m < 4; ++m)
            af[m] = *(const bf16x8*)&Ab[cur][ks][(wr * 64 + m * 16 + rl) * 8];
#pragma unroll
        for (int n = 0; n < 4; ++n)
            bfr[n] = *(const bf16x8*)&Bb[cur][ks][(wc * 64 + n * 16 + rl) * 8];
#pragma unroll
        for (int m = 0; m < 4; ++m)
#pragma unroll
            for (int n = 0; n < 4; ++n)
                acc[m][n] = __builtin_amdgcn_mfma_f32_16x16x32_bf16(af[m], bfr[n], acc[m][n], 0, 0, 0);

        if (t + 1 < KT) writeA(cur ^ 1);
        __syncthreads();
    }

    // epilogue: C/D layout col=lane&15, row=(lane>>4)*4+reg
#pragma unroll
    for (int m = 0; m < 4; ++m) {
#pragma unroll
        for (int n = 0; n < 4; ++n) {
            int gc = col0 + wc * 64 + n * 16 + (lane & 15);
            if (gc >= M) continue;
            float bv = bias ? bias[gc] : 0.f;
#pragma unroll
            for (int r = 0; r < 4; ++r) {
                int grow = row0 + wr * 64 + m * 16 + (lane >> 4) * 4 + r;
                if (grow >= N) continue;
                float v = acc[m][n][r] + bv;
                if (OUT_MODE == 2) v = fmaxf(v, 0.f);
                if (OUT_MODE == 1) ((float*)Cv)[(size_t)grow * M + gc] = v;
                else ((ushort*)Cv)[(size_t)grow * M + gc] = f2b(v);
            }
        }
    }
}

static inline void gemm_bf(const ushort* A, const ushort* Bp, const float* bias, void* C,
                           int N, int M, int K, int mode, hipStream_t s)
{
    dim3 g((N + 127) / 128, (M + 127) / 128);
    if (mode == 0)      gemm_mfma<0><<<g, 256, 0, s>>>(A, Bp, bias, C, N, M, K);
    else if (mode == 1) gemm_mfma<1><<<g, 256, 0, s>>>(A, Bp, bias, C, N, M, K);
    else                gemm_mfma<2><<<g, 256, 0, s>>>(A, Bp, bias, C, N, M, K);
}

// ---------------------------------------------------------------------------
// Fused FF v2: ffout = relu(X @ W1^T + b1) @ W2^T + b2, pre-packed weights.
// Block = 64 rows, 256 threads (4 waves 2x2). 32 f-chunks of 64.
// ---------------------------------------------------------------------------
__global__ __launch_bounds__(256, 2) void ff_fused_kernel(
    const ushort* __restrict__ X, const ushort* __restrict__ W1p,
    const ushort* __restrict__ W2p, const float* __restrict__ b1,
    const float* __restrict__ b2, ushort* __restrict__ ffout, int N)
{
    __shared__ __align__(16) ushort W1buf[32 * 64 * 8];   // [s][frow][8]  32 KB
    __shared__ __align__(16) ushort W2buf[8 * 256 * 8];   // [s2][c][8]    32 KB
    __shared__ __align__(16) ushort Sbuf[8 * 64 * 8];     // [s][row][8]    8 KB
    const int tid = threadIdx.x;
    const int lane = tid & 63;
    const int w = tid >> 6;
    const int wr = w >> 1, wc = w & 1;
    const int row0 = blockIdx.x * 64;
    const int rl = lane & 15;
    const int ks = lane >> 4;

    // persistent X fragments
    bf16x8 xf[2][8];
#pragma unroll
    for (int m = 0; m < 2; ++m) {
        int gr = row0 + wr * 32 + m * 16 + rl;
        if (gr > N - 1) gr = N - 1;
        const ushort* xrow = X + (size_t)gr * 256 + ks * 8;
#pragma unroll
        for (int kc = 0; kc < 8; ++kc)
            xf[m][kc] = *(const bf16x8*)(xrow + kc * 32);
    }

    f32x4 oacc[2][8] = {};

    for (int fc = 0; fc < 32; ++fc) {
        const int f0 = fc * 64;
        // ---- stage packed W1 chunk (32KB) + W2 chunk (32KB), contiguous ----
#pragma unroll
        for (int i = 0; i < 8; ++i) {
            int ii = w * 8 + i;
            const ushort* s1 = W1p + (size_t)fc * 16384 + ii * 512 + lane * 8;
            __builtin_amdgcn_global_load_lds(
                (const __attribute__((address_space(1))) void*)s1,
                (__attribute__((address_space(3))) void*)(W1buf + ii * 512), 16, 0, 0);
            const ushort* s2 = W2p + (size_t)fc * 16384 + ii * 512 + lane * 8;
            __builtin_amdgcn_global_load_lds(
                (const __attribute__((address_space(1))) void*)s2,
                (__attribute__((address_space(3))) void*)(W2buf + ii * 512), 16, 0, 0);
        }
        __syncthreads();

        // ---- phase A: S = relu(X @ W1c^T + b1), 64x64 ----
        f32x4 sacc[2][2] = {};
#pragma unroll
        for (int kc = 0; kc < 8; ++kc) {
            bf16x8 w1f[2];
#pragma unroll
            for (int n = 0; n < 2; ++n)
                w1f[n] = *(const bf16x8*)&W1buf[((kc * 4 + ks) * 64 + wc * 32 + n * 16 + rl) * 8];
#pragma unroll
            for (int m = 0; m < 2; ++m)
#pragma unroll
                for (int n = 0; n < 2; ++n)
                    sacc[m][n] = __builtin_amdgcn_mfma_f32_16x16x32_bf16(xf[m][kc], w1f[n], sacc[m][n], 0, 0, 0);
        }
#pragma unroll
        for (int m = 0; m < 2; ++m)
#pragma unroll
            for (int n = 0; n < 2; ++n) {
                int fl = wc * 32 + n * 16 + rl;
                float bv = b1[f0 + fl];
                int rbase = wr * 32 + m * 16 + ks * 4;
#pragma unroll
                for (int r = 0; r < 4; ++r) {
                    float v = fmaxf(sacc[m][n][r] + bv, 0.f);
                    Sbuf[(fl >> 3) * 512 + (rbase + r) * 8 + (fl & 7)] = f2b(v);
                }
            }
        __syncthreads();

        // ---- phase B: O += S @ W2c^T ----
#pragma unroll
        for (int kc = 0; kc < 2; ++kc) {
            bf16x8 sf[2], w2f[8];
#pragma unroll
            for (int m = 0; m < 2; ++m)
                sf[m] = *(const bf16x8*)&Sbuf[((kc * 4 + ks) * 64 + wr * 32 + m * 16 + rl) * 8];
#pragma unroll
            for (int n = 0; n < 8; ++n)
                w2f[n] = *(const bf16x8*)&W2buf[(kc * 4 + ks) * 2048 + (wc * 128 + n * 16 + rl) * 8];
#pragma unroll
            for (int m = 0; m < 2; ++m)
#pragma unroll
                for (int n = 0; n < 8; ++n)
                    oacc[m][n] = __builtin_amdgcn_mfma_f32_16x16x32_bf16(sf[m], w2f[n], oacc[m][n], 0, 0, 0);
        }
        __syncthreads();
    }

    // ---- epilogue ----
#pragma unroll
    for (int n = 0; n < 8; ++n) {
        int c = wc * 128 + n * 16 + rl;
        float bv = b2[c];
#pragma unroll
        for (int m = 0; m < 2; ++m) {
            int rbase = row0 + wr * 32 + m * 16 + ks * 4;
#pragma unroll
            for (int r = 0; r < 4; ++r) {
                int gr = rbase + r;
                if (gr < N) ffout[(size_t)gr * 256 + c] = f2b(oacc[m][n][r] + bv);
            }
        }
    }
}

// ---------------------------------------------------------------------------
// copy hp(bf16) -> tgt[:,0,:]  (tgt row stride 768)
// ---------------------------------------------------------------------------
__global__ void copy_col0_kernel(const ushort* __restrict__ src, ushort* __restrict__ tgt, int n)
{
    int i = blockIdx.x * blockDim.x + threadIdx.x;
    if (i >= n) return;  // n = NP*64
    int p = i >> 6, c = i & 63;
    ((ushort4*)tgt)[(size_t)p * 192 + c] = ((const ushort4*)src)[(size_t)p * 64 + c];
}

__global__ void zero_ints_kernel(int* __restrict__ p, int n)
{
    int i = blockIdx.x * blockDim.x + threadIdx.x;
    if (i < n) p[i] = 0;
}

// ---------------------------------------------------------------------------
// GAT el/er projections from bf16 h
// ---------------------------------------------------------------------------
__global__ void attn_lr_kernel(const ushort* __restrict__ h, const float* __restrict__ al,
                               const float* __restrict__ ar, float* __restrict__ el,
                               float* __restrict__ er, int N)
{
    int idx = blockIdx.x * blockDim.x + threadIdx.x;
    if (idx >= N * 8) return;
    int hd = idx & 7;
    const ushort* hp = h + (size_t)(idx >> 3) * 256 + hd * 32;
    const float* a1 = al + hd * 32;
    const float* a2 = ar + hd * 32;
    float s1 = 0.f, s2 = 0.f;
#pragma unroll
    for (int j = 0; j < 8; ++j) {
        ushort4 t = ((const ushort4*)hp)[j];
        float v0 = b2f(t.x), v1 = b2f(t.y), v2 = b2f(t.z), v3 = b2f(t.w);
        s1 = fmaf(v0, a1[j * 4 + 0], s1); s2 = fmaf(v0, a2[j * 4 + 0], s2);
        s1 = fmaf(v1, a1[j * 4 + 1], s1); s2 = fmaf(v1, a2[j * 4 + 1], s2);
        s1 = fmaf(v2, a1[j * 4 + 2], s1); s2 = fmaf(v2, a2[j * 4 + 2], s2);
        s1 = fmaf(v3, a1[j * 4 + 3], s1); s2 = fmaf(v3, a2[j * 4 + 3], s2);
    }
    el[idx] = s1;
    er[idx] = s2;
}

// ---------------------------------------------------------------------------
// CSR build
// ---------------------------------------------------------------------------
__global__ void count_deg_kernel(const int* __restrict__ dst, int* __restrict__ deg, int E)
{
    int e = blockIdx.x * blockDim.x + threadIdx.x;
    if (e < E) atomicAdd(&deg[dst[e]], 1);
}

__global__ void exscan_kernel(const int* __restrict__ deg, int* __restrict__ offs, int N)
{
    __shared__ int sbuf[1024];
    __shared__ int carry;
    int tid = threadIdx.x;
    if (tid == 0) carry = 0;
    __syncthreads();
    for (int base = 0; base < N; base += 1024) {
        int i = base + tid;
        int v = (i < N) ? deg[i] : 0;
        sbuf[tid] = v;
        __syncthreads();
        for (int off = 1; off < 1024; off <<= 1) {
            int t = (tid >= off) ? sbuf[tid - off] : 0;
            __syncthreads();
            sbuf[tid] += t;
            __syncthreads();
        }
        if (i < N) offs[i] = carry + sbuf[tid] - v;
        int chunk_total = sbuf[1023];
        __syncthreads();
        if (tid == 0) carry += chunk_total;
        __syncthreads();
    }
    if (tid == 0) offs[N] = carry;
}

__global__ void scatter_kernel(const int* __restrict__ src, const int* __restrict__ dst,
                               const int* __restrict__ offs, int* __restrict__ cur,
                               int* __restrict__ elist, int E)
{
    int e = blockIdx.x * blockDim.x + threadIdx.x;
    if (e >= E) return;
    int d = dst[e];
    int pos = atomicAdd(&cur[d], 1);
    elist[offs[d] + pos] = src[e];
}

// ---------------------------------------------------------------------------
// GAT aggregation: one wave per dst paper; lane owns 4 consecutive cols.
// ---------------------------------------------------------------------------
__global__ __launch_bounds__(64) void gat_agg_kernel(
    const ushort* __restrict__ h, const float* __restrict__ el, const float* __restrict__ er,
    const int* __restrict__ offs, const int* __restrict__ elist,
    const float* __restrict__ bias, ushort* __restrict__ out,
    int Ndst, int self_base, int out_coloff)
{
    int p = blockIdx.x;
    if (p >= Ndst) return;
    int l = threadIdx.x;
    int head = l >> 3;
    int dn = self_base + p;
    float erv = er[(size_t)dn * 8 + head];
    float acc[4] = {0.f, 0.f, 0.f, 0.f};
    float z = 0.f;
    int beg = offs[p], end = offs[p + 1];
    for (int e = beg - 1; e < end; ++e) {
        int s = (e < beg) ? dn : elist[e];
        float x = el[(size_t)s * 8 + head] + erv;
        x = x > 0.f ? x : 0.2f * x;
        float wgt = expf(x);
        z += wgt;
        ushort4 hv = *(const ushort4*)&h[(size_t)s * 256 + l * 4];
        acc[0] = fmaf(wgt, b2f(hv.x), acc[0]);
        acc[1] = fmaf(wgt, b2f(hv.y), acc[1]);
        acc[2] = fmaf(wgt, b2f(hv.z), acc[2]);
        acc[3] = fmaf(wgt, b2f(hv.w), acc[3]);
    }
    float inv = 1.f / z;
    ushort4 o;
    o.x = f2b(acc[0] * inv + bias[l * 4 + 0]);
    o.y = f2b(acc[1] * inv + bias[l * 4 + 1]);
    o.z = f2b(acc[2] * inv + bias[l * 4 + 2]);
    o.w = f2b(acc[3] * inv + bias[l * 4 + 3]);
    *(ushort4*)&out[(size_t)p * 768 + out_coloff + l * 4] = o;
}

// ---------------------------------------------------------------------------
// Tiny MHA (S=Sk=3): one thread per (paper, query, head); bf16 in/out.
// ---------------------------------------------------------------------------
__global__ void mha3_kernel(const ushort* __restrict__ qb, int ldq, int qoff,
                            const ushort* __restrict__ kvb, int ldkv, int koff, int voff,
                            ushort* __restrict__ ob, int NPn)
{
    int idx = blockIdx.x * blockDim.x + threadIdx.x;
    if (idx >= NPn * 24) return;
    int h = idx & 7;
    int i = (idx >> 3) % 3;
    int p = idx / 24;
    float qr[32];
    {
        const ushort* q = qb + (size_t)(p * 3 + i) * ldq + qoff + h * 32;
#pragma unroll
        for (int j = 0; j < 8; ++j) {
            ushort4 t = ((const ushort4*)q)[j];
            qr[j * 4 + 0] = b2f(t.x); qr[j * 4 + 1] = b2f(t.y);
            qr[j * 4 + 2] = b2f(t.z); qr[j * 4 + 3] = b2f(t.w);
        }
    }
    float s[3];
#pragma unroll
    for (int j = 0; j < 3; ++j) {
        const ushort* k = kvb + (size_t)(p * 3 + j) * ldkv + koff + h * 32;
        float a = 0.f;
#pragma unroll
        for (int t4 = 0; t4 < 8; ++t4) {
            ushort4 t = ((const ushort4*)k)[t4];
            a = fmaf(qr[t4 * 4 + 0], b2f(t.x), a);
            a = fmaf(qr[t4 * 4 + 1], b2f(t.y), a);
            a = fmaf(qr[t4 * 4 + 2], b2f(t.z), a);
            a = fmaf(qr[t4 * 4 + 3], b2f(t.w), a);
        }
        s[j] = a * 0.17677669529663687f;
    }
    float m = fmaxf(s[0], fmaxf(s[1], s[2]));
    float e0 = expf(s[0] - m), e1 = expf(s[1] - m), e2 = expf(s[2] - m);
    float inv = 1.f / (e0 + e1 + e2);
    float aw[3] = {e0 * inv, e1 * inv, e2 * inv};
    float o[32] = {};
#pragma unroll
    for (int j = 0; j < 3; ++j) {
        const ushort* v = kvb + (size_t)(p * 3 + j) * ldkv + voff + h * 32;
#pragma unroll
        for (int t4 = 0; t4 < 8; ++t4) {
            ushort4 t = ((const ushort4*)v)[t4];
            o[t4 * 4 + 0] = fmaf(aw[j], b2f(t.x), o[t4 * 4 + 0]);
            o[t4 * 4 + 1] = fmaf(aw[j], b2f(t.y), o[t4 * 4 + 1]);
            o[t4 * 4 + 2] = fmaf(aw[j], b2f(t.z), o[t4 * 4 + 2]);
            o[t4 * 4 + 3] = fmaf(aw[j], b2f(t.w), o[t4 * 4 + 3]);
        }
    }
    ushort* op = ob + (size_t)(p * 3 + i) * 256 + h * 32;
#pragma unroll
    for (int t4 = 0; t4 < 8; ++t4) {
        ushort4 t;
        t.x = f2b(o[t4 * 4 + 0]); t.y = f2b(o[t4 * 4 + 1]);
        t.z = f2b(o[t4 * 4 + 2]); t.w = f2b(o[t4 * 4 + 3]);
        ((ushort4*)op)[t4] = t;
    }
}

// ---------------------------------------------------------------------------
// Fused residual add + LayerNorm (256 ch), bf16 in/out, wave per row.
// ---------------------------------------------------------------------------
__global__ __launch_bounds__(256) void add_ln_kernel(
    const ushort* __restrict__ a, const ushort* __restrict__ b,
    const float* __restrict__ g, const float* __restrict__ be,
    ushort* __restrict__ out, int rows)
{
    int row = blockIdx.x * 4 + (threadIdx.x >> 6);
    if (row >= rows) return;
    int l = threadIdx.x & 63;
    ushort4 va = *(const ushort4*)&a[(size_t)row * 256 + l * 4];
    ushort4 vb = *(const ushort4*)&b[(size_t)row * 256 + l * 4];
    float v[4];
    v[0] = b2f(va.x) + b2f(vb.x);
    v[1] = b2f(va.y) + b2f(vb.y);
    v[2] = b2f(va.z) + b2f(vb.z);
    v[3] = b2f(va.w) + b2f(vb.w);
    float s = v[0] + v[1] + v[2] + v[3];
#pragma unroll
    for (int off = 32; off; off >>= 1) s += __shfl_xor(s, off);
    float mean = s * (1.f / 256.f);
    float s2 = 0.f;
#pragma unroll
    for (int j = 0; j < 4; ++j) { float d = v[j] - mean; s2 = fmaf(d, d, s2); }
#pragma unroll
    for (int off = 32; off; off >>= 1) s2 += __shfl_xor(s2, off);
    float rstd = rsqrtf(s2 * (1.f / 256.f) + 1e-5f);
    ushort4 o;
    o.x = f2b((v[0] - mean) * rstd * g[l * 4 + 0] + be[l * 4 + 0]);
    o.y = f2b((v[1] - mean) * rstd * g[l * 4 + 1] + be[l * 4 + 1]);
    o.z = f2b((v[2] - mean) * rstd * g[l * 4 + 2] + be[l * 4 + 2]);
    o.w = f2b((v[3] - mean) * rstd * g[l * 4 + 3] + be[l * 4 + 3]);
    *(ushort4*)&out[(size_t)row * 256 + l * 4] = o;
}

// ---------------------------------------------------------------------------
// kernel_launch — ws layout (bytes):
// [0, 30.72M)        tgt_bf (60000x256 bf16)
// [30.72M, 61.44M)   X_bf
// [61.44M, 65.28M)   packed weights (3.74 MB used)
// [65.28M, ...)      BIG, era-overlaid (max era ~77 MB -> total ~142 MB)
// ---------------------------------------------------------------------------
extern "C" void kernel_launch(void* const* d_in, const int* in_sizes, int n_in,
                              void* d_out, int out_size, void* d_ws, size_t ws_size,
                              hipStream_t stream)
{
    const float* feat_paper  = (const float*)d_in[0];
    const float* feat_author = (const float*)d_in[1];
    const float* W_in_p  = (const float*)d_in[2];
    const float* b_in_p  = (const float*)d_in[3];
    const float* W_in_a  = (const float*)d_in[4];
    const float* b_in_a  = (const float*)d_in[5];
    const float* W_gat_ap = (const float*)d_in[6];
    const float* al_ap    = (const float*)d_in[7];
    const float* ar_ap    = (const float*)d_in[8];
    const float* b_gat_ap = (const float*)d_in[9];
    const float* W_gat_pp = (const float*)d_in[10];
    const float* al_pp    = (const float*)d_in[11];
    const float* ar_pp    = (const float*)d_in[12];
    const float* b_gat_pp = (const float*)d_in[13];
    const float* Wqkv_s = (const float*)d_in[14];
    const float* bqkv_s = (const float*)d_in[15];
    const float* Wo_s   = (const float*)d_in[16];
    const float* bo_s   = (const float*)d_in[17];
    const float* Wqkv_c = (const float*)d_in[18];
    const float* bqkv_c = (const float*)d_in[19];
    const float* Wo_c   = (const float*)d_in[20];
    const float* bo_c   = (const float*)d_in[21];
    const float* W_ff1  = (const float*)d_in[22];
    const float* b_ff1  = (const float*)d_in[23];
    const float* W_ff2  = (const float*)d_in[24];
    const float* b_ff2  = (const float*)d_in[25];
    const float* ln1_g  = (const float*)d_in[26];
    const float* ln1_b  = (const float*)d_in[27];
    const float* ln2_g  = (const float*)d_in[28];
    const float* ln2_b  = (const float*)d_in[29];
    const float* ln3_g  = (const float*)d_in[30];
    const float* ln3_b  = (const float*)d_in[31];
    const float* W_pred = (const float*)d_in[32];
    const float* b_pred = (const float*)d_in[33];
    const int* ap_src = (const int*)d_in[34];
    const int* ap_dst = (const int*)d_in[35];
    const int* pp_src = (const int*)d_in[36];
    const int* pp_dst = (const int*)d_in[37];

    const int NP = NP_N, NA = NA_N;

    uint8_t* wsb = (uint8_t*)d_ws;
    ushort* tgt_bf = (ushort*)wsb;
    ushort* X_bf   = (ushort*)(wsb + 30720000);
    ushort* WB     = (ushort*)(wsb + 61440000);
    // packed weight offsets (ushort elems)
    ushort* p_in_p   = WB + 0;        // 32768
    ushort* p_in_a   = WB + 32768;    // 32768
    ushort* p_gat_ap = WB + 65536;    // 65536
    ushort* p_gat_pp = WB + 131072;   // 65536
    ushort* p_qkv_s  = WB + 196608;   // 196608
    ushort* p_o_s    = WB + 393216;   // 65536
    ushort* p_qkv_c  = WB + 458752;   // 196608
    ushort* p_o_c    = WB + 655360;   // 65536
    ushort* p_pred   = WB + 720896;   // 98304 (M padded to 128)
    ushort* p_ff1    = WB + 819200;   // 524288
    ushort* p_ff2    = WB + 1343488;  // 524288
    uint8_t* BIG = wsb + 65280000;

    auto packB = [&](const float* W, ushort* out, int M, int K) {
        int nquad = (((M + 127) >> 7) << 7) * K / 4;
        packB_kernel<<<(nquad + 255) / 256, 256, 0, stream>>>(W, out, M, K, nquad);
    };

    // era A overlay inside BIG
    ushort* feat_p_bf = (ushort*)BIG;
    ushort* feat_a_bf = (ushort*)(BIG + 5120000);
    ushort* x_ap_bf   = (ushort*)(BIG + 10240000);
    ushort* hp_bf     = x_ap_bf + (size_t)NA * 256;
    ushort* h_ap_bf   = (ushort*)(BIG + 30720000);
    ushort* h_pp_bf   = (ushort*)(BIG + 51200000);
    float* el_ap = (float*)(BIG + 61440000);
    float* er_ap = (float*)(BIG + 62720000);
    float* el_pp = (float*)(BIG + 64000000);
    float* er_pp = (float*)(BIG + 64640000);
    int* ireg    = (int*)(BIG + 65280000);
    int* ap_offs = ireg;
    int* pp_offs = ireg + 20001;
    int* ap_cur  = ireg + 40002;
    int* pp_cur  = ireg + 60002;
    int* ap_list = ireg + 80002;
    int* pp_list = ireg + 480002;

    // ---- feature converts + weight packs ----
    cvt_kernel<<<(NP * 128 / 4 + 255) / 256, 256, 0, stream>>>(feat_paper, feat_p_bf, NP * 128 / 4);
    cvt_kernel<<<(NA * 128 / 4 + 255) / 256, 256, 0, stream>>>(feat_author, feat_a_bf, NA * 128 / 4);
    packB(W_in_p, p_in_p, 256, 128);
    packB(W_in_a, p_in_a, 256, 128);
    packB(W_gat_ap, p_gat_ap, 256, 256);
    packB(W_gat_pp, p_gat_pp, 256, 256);
    packB(Wqkv_s, p_qkv_s, 768, 256);
    packB(Wo_s, p_o_s, 256, 256);
    packB(Wqkv_c, p_qkv_c, 768, 256);
    packB(Wo_c, p_o_c, 256, 256);
    packB(W_pred, p_pred, 64, 768);
    packW1_kernel<<<512, 256, 0, stream>>>(W_ff1, p_ff1);
    packW2_kernel<<<512, 256, 0, stream>>>(W_ff2, p_ff2);

    // ---- input projections (bf16 out) ----
    gemm_bf(feat_a_bf, p_in_a, b_in_a, x_ap_bf, NA, 256, 128, 0, stream);
    gemm_bf(feat_p_bf, p_in_p, b_in_p, hp_bf,   NP, 256, 128, 0, stream);

    // tgt[:,0,:] = hp
    copy_col0_kernel<<<(NP * 64 + 255) / 256, 256, 0, stream>>>(hp_bf, tgt_bf, NP * 64);

    // ---- GAT feature transforms (no bias) ----
    gemm_bf(x_ap_bf, p_gat_ap, nullptr, h_ap_bf, NA + NP, 256, 256, 0, stream);
    gemm_bf(hp_bf,   p_gat_pp, nullptr, h_pp_bf, NP,      256, 256, 0, stream);

    // ---- el/er ----
    attn_lr_kernel<<<(40000 * 8 + 255) / 256, 256, 0, stream>>>(h_ap_bf, al_ap, ar_ap, el_ap, er_ap, 40000);
    attn_lr_kernel<<<(20000 * 8 + 255) / 256, 256, 0, stream>>>(h_pp_bf, al_pp, ar_pp, el_pp, er_pp, 20000);

    // ---- CSR build ----
    zero_ints_kernel<<<(40000 + 255) / 256, 256, 0, stream>>>(ap_cur, 40000);
    count_deg_kernel<<<(E_AP_N + 255) / 256, 256, 0, stream>>>(ap_dst, ap_cur, E_AP_N);
    count_deg_kernel<<<(E_PP_N + 255) / 256, 256, 0, stream>>>(pp_dst, pp_cur, E_PP_N);
    exscan_kernel<<<1, 1024, 0, stream>>>(ap_cur, ap_offs, NP);
    exscan_kernel<<<1, 1024, 0, stream>>>(pp_cur, pp_offs, NP);
    zero_ints_kernel<<<(40000 + 255) / 256, 256, 0, stream>>>(ap_cur, 40000);
    scatter_kernel<<<(E_AP_N + 255) / 256, 256, 0, stream>>>(ap_src, ap_dst, ap_offs, ap_cur, ap_list, E_AP_N);
    scatter_kernel<<<(E_PP_N + 255) / 256, 256, 0, stream>>>(pp_src, pp_dst, pp_offs, pp_cur, pp_list, E_PP_N);

    // ---- GAT aggregation -> tgt slots 1,2 ----
    gat_agg_kernel<<<NP, 64, 0, stream>>>(h_ap_bf, el_ap, er_ap, ap_offs, ap_list, b_gat_ap, tgt_bf, NP, NA, 256);
    gat_agg_kernel<<<NP, 64, 0, stream>>>(h_pp_bf, el_pp, er_pp, pp_offs, pp_list, b_gat_pp, tgt_bf, NP, 0, 512);

    // ---- self attention: 2 chunks of 30000 rows (10000 papers) ----
    {
        ushort* qkv  = (ushort*)BIG;
        ushort* obuf = (ushort*)(BIG + 46080000);
        ushort* proj = (ushort*)(BIG + 61440000);
        for (int c = 0; c < 2; ++c) {
            size_t ro = (size_t)c * 30000 * 256;
            gemm_bf(tgt_bf + ro, p_qkv_s, bqkv_s, qkv, 30000, 768, 256, 0, stream);
            mha3_kernel<<<(10000 * 24 + 255) / 256, 256, 0, stream>>>(qkv, 768, 0, qkv, 768, 256, 512, obuf, 10000);
            gemm_bf(obuf, p_o_s, bo_s, proj, 30000, 256, 256, 0, stream);
            add_ln_kernel<<<30000 / 4, 256, 0, stream>>>(tgt_bf + ro, proj, ln1_g, ln1_b, X_bf + ro, 30000);
        }
    }

    // ---- cross attention: 2 chunks of 30000 rows ----
    {
        ushort* qb   = (ushort*)BIG;
        ushort* kvb  = (ushort*)(BIG + 15360000);
        ushort* obuf = (ushort*)(BIG + 46080000);
        ushort* proj = (ushort*)(BIG + 61440000);
        // kv GEMM uses col-tiles 2..5 of the 768-row qkv_c pack (256 = tile boundary)
        const ushort* p_kv_c = p_qkv_c + (size_t)2 * (256 / 32) * 4096;
        for (int c = 0; c < 2; ++c) {
            size_t ro = (size_t)c * 30000 * 256;
            gemm_bf(X_bf + ro,   p_qkv_c, bqkv_c,       qb,  30000, 256, 256, 0, stream);
            gemm_bf(tgt_bf + ro, p_kv_c,  bqkv_c + 256, kvb, 30000, 512, 256, 0, stream);
            mha3_kernel<<<(10000 * 24 + 255) / 256, 256, 0, stream>>>(qb, 256, 0, kvb, 512, 0, 256, obuf, 10000);
            gemm_bf(obuf, p_o_c, bo_c, proj, 30000, 256, 256, 0, stream);
            add_ln_kernel<<<30000 / 4, 256, 0, stream>>>(X_bf + ro, proj, ln2_g, ln2_b, X_bf + ro, 30000);
        }
    }

    // ---- feed-forward: single fused dispatch over all 60000 rows ----
    {
        ushort* ffo = (ushort*)BIG;   // 30.72 MB
        ff_fused_kernel<<<(60000 + 63) / 64, 256, 0, stream>>>(X_bf, p_ff1, p_ff2, b_ff1, b_ff2, ffo, 60000);
        add_ln_kernel<<<60000 / 4, 256, 0, stream>>>(X_bf, ffo, ln3_g, ln3_b, X_bf, 60000);
    }

    // ---- prediction head: X viewed as (20000,768) @ W_pred^T -> f32 d_out ----
    gemm_bf(X_bf, p_pred, b_pred, (float*)d_out, NP, 64, 768, 1, stream);
}

// Round 6
// 817.256 us; speedup vs baseline: 7.4957x; 1.1563x over previous
//
#include <hip/hip_runtime.h>
#include <hip/hip_bf16.h>
#include <cstdint>
#include <cstddef>

#define NP_N 20000
#define NA_N 20000
#define E_AP_N 400000
#define E_PP_N 400000
// D_IN=128, D_H=256, HEADS=8, D_HEAD=32, D_FF=2048, D_OUT=64

typedef __attribute__((ext_vector_type(8))) short bf16x8;
typedef __attribute__((ext_vector_type(4))) float f32x4;

__device__ __forceinline__ float b2f(ushort u) { return __uint_as_float(((uint32_t)u) << 16); }
__device__ __forceinline__ ushort f2b(float f) {
    uint32_t x = __float_as_uint(f);
    return (ushort)((x + 0x7fffu + ((x >> 16) & 1u)) >> 16);  // RNE (no NaN inputs here)
}

#define LGKM_BARRIER() do { \
    asm volatile("s_waitcnt lgkmcnt(0)" ::: "memory"); \
    __builtin_amdgcn_s_barrier(); \
    __builtin_amdgcn_sched_barrier(0); \
} while (0)

// ---------------------------------------------------------------------------
// Mega pack kernel: one dispatch does all f32->bf16 converts + weight packs
// + counter zeroing. Job types: 0=packB(gemm staging order), 1=packW1(ff),
// 2=packW2(ff), 3=cvt row-order, 4=zero int4s.
// ---------------------------------------------------------------------------
#define NJOBS 14
struct PackJobs {
    const float* src[NJOBS];
    void* dst[NJOBS];
    int M[NJOBS], K[NJOBS];
    int type[NJOBS];
    int nquad[NJOBS];
    int blk0[NJOBS];
};

__global__ void pack_all_kernel(PackJobs J)
{
    int b = blockIdx.x;
    int j = 0;
    while (j + 1 < NJOBS && b >= J.blk0[j + 1]) ++j;
    int u = (b - J.blk0[j]) * 256 + threadIdx.x;
    if (u >= J.nquad[j]) return;
    int ty = J.type[j];
    const float* src = J.src[j];
    if (ty == 3) {
        float4 v = ((const float4*)src)[u];
        ushort4 o;
        o.x = f2b(v.x); o.y = f2b(v.y); o.z = f2b(v.z); o.w = f2b(v.w);
        ((ushort4*)J.dst[j])[u] = o;
    } else if (ty == 4) {
        int4 z = {0, 0, 0, 0};
        ((int4*)J.dst[j])[u] = z;
    } else if (ty == 0) {
        // out[(jt*KT+t)*4096 + ks*1024 + r*8 + e] = B[jt*128+r][t*32+ks*8+e]
        int M = J.M[j], K = J.K[j];
        int KT = K >> 5;
        int q = u & 1023;
        int jt = u >> 10;
        int t = jt % KT, jj = jt / KT;
        int ks = q >> 8, rem = q & 255;
        int r = rem >> 1;
        int e0 = (rem & 1) * 4;
        int row = jj * 128 + r;
        ushort4 o = {0, 0, 0, 0};
        if (row < M) {
            const float* s = src + (size_t)row * K + t * 32 + ks * 8 + e0;
            o.x = f2b(s[0]); o.y = f2b(s[1]); o.z = f2b(s[2]); o.w = f2b(s[3]);
        }
        ((ushort4*)J.dst[j])[u] = o;
    } else if (ty == 1) {
        // W1(2048,256) -> [chunk64][s32][f32][8]
        int q = u & 2047, chunk = u >> 11;
        int s = q >> 6, rem = q & 63;
        int fl = rem >> 1, e0 = (rem & 1) * 4;
        const float* sp = src + (size_t)(chunk * 32 + fl) * 256 + s * 8 + e0;
        ushort4 o;
        o.x = f2b(sp[0]); o.y = f2b(sp[1]); o.z = f2b(sp[2]); o.w = f2b(sp[3]);
        ((ushort4*)J.dst[j])[u] = o;
    } else {
        // W2(256,2048) -> [chunk64][s2 4][c256][8]
        int q = u & 2047, chunk = u >> 11;
        int s2 = q >> 9, rem = q & 511;
        int c = rem >> 1, e0 = (rem & 1) * 4;
        const float* sp = src + (size_t)c * 2048 + chunk * 32 + s2 * 8 + e0;
        ushort4 o;
        o.x = f2b(sp[0]); o.y = f2b(sp[1]); o.z = f2b(sp[2]); o.w = f2b(sp[3]);
        ((ushort4*)J.dst[j])[u] = o;
    }
}

// ---------------------------------------------------------------------------
// bf16 MFMA GEMM: C(N,M) = A(N,K) @ B(M,K)^T + bias. A row stride = lda.
// A reg-staged + ds_write; B pre-packed contiguous global_load_lds.
// 128x128 tile, BK=32, double-buffered, one barrier per K-step.
// OUT_MODE: 0 = bf16, 1 = f32, 2 = bf16 + relu
// ---------------------------------------------------------------------------
template <int OUT_MODE>
__global__ __launch_bounds__(256) void gemm_mfma(
    const ushort* __restrict__ A, const ushort* __restrict__ Bp,
    const float* __restrict__ bias, void* __restrict__ Cv,
    int N, int M, int K, int lda)
{
    __shared__ __align__(16) ushort Ab[2][4][128 * 8];
    __shared__ __align__(16) ushort Bb[2][4][128 * 8];
    const int tid = threadIdx.x;
    const int lane = tid & 63;
    const int w = tid >> 6;
    const int wr = w >> 1, wc = w & 1;
    const int row0 = blockIdx.x * 128;
    const int col0 = blockIdx.y * 128;
    const int KT = K >> 5;
    const ushort* Bbase = Bp + (size_t)blockIdx.y * KT * 4096;
    f32x4 acc[4][4] = {};

    const int rsub = lane >> 2, ksl = lane & 3;
    int arow[2];
#pragma unroll
    for (int j = 0; j < 2; ++j) {
        int r = row0 + w * 32 + j * 16 + rsub;
        arow[j] = (r < N) ? r : (N - 1);
    }

    bf16x8 areg[2];
    auto loadA = [&](int k0) {
#pragma unroll
        for (int j = 0; j < 2; ++j)
            areg[j] = *(const bf16x8*)(A + (size_t)arow[j] * lda + k0 + ksl * 8);
    };
    auto writeA = [&](int buf) {
#pragma unroll
        for (int j = 0; j < 2; ++j)
            *(bf16x8*)&Ab[buf][ksl][(w * 32 + j * 16 + rsub) * 8] = areg[j];
    };
    auto gloadB = [&](int buf, int t) {
#pragma unroll
        for (int i = 0; i < 2; ++i) {
            const ushort* src = Bbase + (size_t)t * 4096 + (w * 2 + i) * 512 + lane * 8;
            ushort* dst = (ushort*)Bb[buf] + (w * 2 + i) * 512;
            __builtin_amdgcn_global_load_lds(
                (const __attribute__((address_space(1))) void*)src,
                (__attribute__((address_space(3))) void*)dst, 16, 0, 0);
        }
    };

    loadA(0);
    gloadB(0, 0);
    writeA(0);
    __syncthreads();

    for (int t = 0; t < KT; ++t) {
        const int cur = t & 1;
        if (t + 1 < KT) { loadA((t + 1) << 5); gloadB(cur ^ 1, t + 1); }

        bf16x8 af[4], bfr[4];
        const int ks = lane >> 4;
        const int rl = lane & 15;
#pragma unroll
        for (int m = 0; m < 4; ++m)
            af[m] = *(const bf16x8*)&Ab[cur][ks][(wr * 64 + m * 16 + rl) * 8];
#pragma unroll
        for (int n = 0; n < 4; ++n)
            bfr[n] = *(const bf16x8*)&Bb[cur][ks][(wc * 64 + n * 16 + rl) * 8];
#pragma unroll
        for (int m = 0; m < 4; ++m)
#pragma unroll
            for (int n = 0; n < 4; ++n)
                acc[m][n] = __builtin_amdgcn_mfma_f32_16x16x32_bf16(af[m], bfr[n], acc[m][n], 0, 0, 0);

        if (t + 1 < KT) writeA(cur ^ 1);
        __syncthreads();
    }

#pragma unroll
    for (int m = 0; m < 4; ++m) {
#pragma unroll
        for (int n = 0; n < 4; ++n) {
            int gc = col0 + wc * 64 + n * 16 + (lane & 15);
            if (gc >= M) continue;
            float bv = bias ? bias[gc] : 0.f;
#pragma unroll
            for (int r = 0; r < 4; ++r) {
                int grow = row0 + wr * 64 + m * 16 + (lane >> 4) * 4 + r;
                if (grow >= N) continue;
                float v = acc[m][n][r] + bv;
                if (OUT_MODE == 2) v = fmaxf(v, 0.f);
                if (OUT_MODE == 1) ((float*)Cv)[(size_t)grow * M + gc] = v;
                else ((ushort*)Cv)[(size_t)grow * M + gc] = f2b(v);
            }
        }
    }
}

static inline void gemm_bf(const ushort* A, const ushort* Bp, const float* bias, void* C,
                           int N, int M, int K, int lda, int mode, hipStream_t s)
{
    dim3 g((N + 127) / 128, (M + 127) / 128);
    if (mode == 0)      gemm_mfma<0><<<g, 256, 0, s>>>(A, Bp, bias, C, N, M, K, lda);
    else if (mode == 1) gemm_mfma<1><<<g, 256, 0, s>>>(A, Bp, bias, C, N, M, K, lda);
    else                gemm_mfma<2><<<g, 256, 0, s>>>(A, Bp, bias, C, N, M, K, lda);
}

// ---------------------------------------------------------------------------
// Fused FF v3: ffout = relu(X @ W1^T + b1) @ W2^T + b2.
// 64 rows/block, 256 thr (4 waves 2x2), f-chunk 32, 64 chunks.
// Double-buffered weight staging; mid-chunk barrier is lgkmcnt-only (weight
// prefetch stays in flight across it); phase A uses swapped operands
// (A=W1, B=X) so S writes are conflict-free ushort4 stores.
// ---------------------------------------------------------------------------
__global__ __launch_bounds__(256, 2) void ff_fused_kernel(
    const ushort* __restrict__ X, const ushort* __restrict__ W1p,
    const ushort* __restrict__ W2p, const float* __restrict__ b1,
    const float* __restrict__ b2, ushort* __restrict__ ffout, int N)
{
    __shared__ __align__(16) ushort W1buf[2][8192];  // [s32][f32][8] 16KB each
    __shared__ __align__(16) ushort W2buf[2][8192];  // [s2 4][c256][8]
    __shared__ __align__(16) ushort Sbuf[2048];      // [s 4][row64][8] 4KB
    const int tid = threadIdx.x;
    const int lane = tid & 63;
    const int w = tid >> 6;
    const int wr = w >> 1, wc = w & 1;
    const int row0 = blockIdx.x * 64;
    const int rl = lane & 15;
    const int ks = lane >> 4;

    // persistent X fragments: wave's 32 rows
    bf16x8 xf[2][8];
#pragma unroll
    for (int m = 0; m < 2; ++m) {
        int gr = row0 + wr * 32 + m * 16 + rl;
        if (gr > N - 1) gr = N - 1;
        const ushort* xrow = X + (size_t)gr * 256 + ks * 8;
#pragma unroll
        for (int kc = 0; kc < 8; ++kc)
            xf[m][kc] = *(const bf16x8*)(xrow + kc * 32);
    }

    f32x4 oacc[2][8] = {};

    auto stage = [&](int buf, int fc) {
#pragma unroll
        for (int i = 0; i < 8; ++i) {
            int ii = w * 8 + i;
            const ushort* src;
            ushort* dst;
            if (ii < 16) {
                src = W1p + (size_t)fc * 8192 + ii * 512 + lane * 8;
                dst = &W1buf[buf][ii * 512];
            } else {
                src = W2p + (size_t)fc * 8192 + (ii - 16) * 512 + lane * 8;
                dst = &W2buf[buf][(ii - 16) * 512];
            }
            __builtin_amdgcn_global_load_lds(
                (const __attribute__((address_space(1))) void*)src,
                (__attribute__((address_space(3))) void*)dst, 16, 0, 0);
        }
    };

    stage(0, 0);
    __syncthreads();

    for (int fc = 0; fc < 64; ++fc) {
        const int cur = fc & 1;
        if (fc + 1 < 64) stage(cur ^ 1, fc + 1);

        // ---- phase A (swapped): S[f][row] = relu(W1c @ X^T + b1) ----
        f32x4 sacc[2] = {};
#pragma unroll
        for (int kc = 0; kc < 8; ++kc) {
            bf16x8 w1f = *(const bf16x8*)&W1buf[cur][(kc * 4 + ks) * 256 + (wc * 16 + rl) * 8];
#pragma unroll
            for (int m = 0; m < 2; ++m)
                sacc[m] = __builtin_amdgcn_mfma_f32_16x16x32_bf16(w1f, xf[m][kc], sacc[m], 0, 0, 0);
        }
        {
            const int f0 = fc * 32;
            const int fb = wc * 16 + ks * 4;
            const int sidx = wc * 2 + (ks >> 1);
            const int e0 = (ks & 1) * 4;
#pragma unroll
            for (int m = 0; m < 2; ++m) {
                ushort4 o;
                o.x = f2b(fmaxf(sacc[m][0] + b1[f0 + fb + 0], 0.f));
                o.y = f2b(fmaxf(sacc[m][1] + b1[f0 + fb + 1], 0.f));
                o.z = f2b(fmaxf(sacc[m][2] + b1[f0 + fb + 2], 0.f));
                o.w = f2b(fmaxf(sacc[m][3] + b1[f0 + fb + 3], 0.f));
                *(ushort4*)&Sbuf[(sidx * 64 + wr * 32 + m * 16 + rl) * 8 + e0] = o;
            }
        }
        LGKM_BARRIER();  // S visible; weight prefetch stays in flight

        // ---- phase B: O += S @ W2c^T (single K-step of 32) ----
        {
            bf16x8 sf[2];
#pragma unroll
            for (int m = 0; m < 2; ++m)
                sf[m] = *(const bf16x8*)&Sbuf[(ks * 512 + (wr * 32 + m * 16 + rl) * 8)];
#pragma unroll
            for (int n = 0; n < 8; ++n) {
                bf16x8 w2f = *(const bf16x8*)&W2buf[cur][ks * 2048 + (wc * 128 + n * 16 + rl) * 8];
#pragma unroll
                for (int m = 0; m < 2; ++m)
                    oacc[m][n] = __builtin_amdgcn_mfma_f32_16x16x32_bf16(sf[m], w2f, oacc[m][n], 0, 0, 0);
            }
        }
        __syncthreads();  // drains prefetch (vmcnt) + S reads before next chunk
    }

#pragma unroll
    for (int n = 0; n < 8; ++n) {
        int c = wc * 128 + n * 16 + rl;
        float bv = b2[c];
#pragma unroll
        for (int m = 0; m < 2; ++m) {
            int rbase = row0 + wr * 32 + m * 16 + ks * 4;
#pragma unroll
            for (int r = 0; r < 4; ++r) {
                int gr = rbase + r;
                if (gr < N) ffout[(size_t)gr * 256 + c] = f2b(oacc[m][n][r] + bv);
            }
        }
    }
}

// ---------------------------------------------------------------------------
// copy hp(bf16) -> tgt[:,0,:]  (tgt row stride 768)
// ---------------------------------------------------------------------------
__global__ void copy_col0_kernel(const ushort* __restrict__ src, ushort* __restrict__ tgt, int n)
{
    int i = blockIdx.x * blockDim.x + threadIdx.x;
    if (i >= n) return;  // n = NP*64
    int p = i >> 6, c = i & 63;
    ((ushort4*)tgt)[(size_t)p * 192 + c] = ((const ushort4*)src)[(size_t)p * 64 + c];
}

// ---------------------------------------------------------------------------
// GAT el/er projections, both node sets in one dispatch
// ---------------------------------------------------------------------------
__global__ void attn_lr_all_kernel(
    const ushort* __restrict__ h0, const float* __restrict__ al0, const float* __restrict__ ar0,
    float* __restrict__ el0, float* __restrict__ er0,
    const ushort* __restrict__ h1, const float* __restrict__ al1, const float* __restrict__ ar1,
    float* __restrict__ el1, float* __restrict__ er1)
{
    int idx = blockIdx.x * blockDim.x + threadIdx.x;
    if (idx >= 480000) return;
    const ushort* h; const float *a1, *a2; float *el, *er; int i;
    if (idx < 320000) { h = h0; a1 = al0; a2 = ar0; el = el0; er = er0; i = idx; }
    else { h = h1; a1 = al1; a2 = ar1; el = el1; er = er1; i = idx - 320000; }
    int hd = i & 7;
    const ushort* hp = h + (size_t)(i >> 3) * 256 + hd * 32;
    const float* p1 = a1 + hd * 32;
    const float* p2 = a2 + hd * 32;
    float s1 = 0.f, s2 = 0.f;
#pragma unroll
    for (int j = 0; j < 8; ++j) {
        ushort4 t = ((const ushort4*)hp)[j];
        float v0 = b2f(t.x), v1 = b2f(t.y), v2 = b2f(t.z), v3 = b2f(t.w);
        s1 = fmaf(v0, p1[j * 4 + 0], s1); s2 = fmaf(v0, p2[j * 4 + 0], s2);
        s1 = fmaf(v1, p1[j * 4 + 1], s1); s2 = fmaf(v1, p2[j * 4 + 1], s2);
        s1 = fmaf(v2, p1[j * 4 + 2], s1); s2 = fmaf(v2, p2[j * 4 + 2], s2);
        s1 = fmaf(v3, p1[j * 4 + 3], s1); s2 = fmaf(v3, p2[j * 4 + 3], s2);
    }
    el[i] = s1;
    er[i] = s2;
}

// ---------------------------------------------------------------------------
// CSR build: dual count, dual scan (+re-zero), dual scatter
// ---------------------------------------------------------------------------
__global__ void count2_kernel(const int* __restrict__ d0, int* __restrict__ c0,
                              const int* __restrict__ d1, int* __restrict__ c1, int E)
{
    int e = blockIdx.x * blockDim.x + threadIdx.x;
    if (e < E) atomicAdd(&c0[d0[e]], 1);
    else if (e < 2 * E) atomicAdd(&c1[d1[e - E]], 1);
}

__global__ void exscan2_kernel(int* __restrict__ deg0, int* __restrict__ offs0,
                               int* __restrict__ deg1, int* __restrict__ offs1, int N)
{
    int* deg = blockIdx.x ? deg1 : deg0;
    int* offs = blockIdx.x ? offs1 : offs0;
    __shared__ int sbuf[1024];
    __shared__ int carry;
    int tid = threadIdx.x;
    if (tid == 0) carry = 0;
    __syncthreads();
    for (int base = 0; base < N; base += 1024) {
        int i = base + tid;
        int v = (i < N) ? deg[i] : 0;
        sbuf[tid] = v;
        __syncthreads();
        for (int off = 1; off < 1024; off <<= 1) {
            int t = (tid >= off) ? sbuf[tid - off] : 0;
            __syncthreads();
            sbuf[tid] += t;
            __syncthreads();
        }
        if (i < N) offs[i] = carry + sbuf[tid] - v;
        int chunk_total = sbuf[1023];
        __syncthreads();
        if (tid == 0) carry += chunk_total;
        __syncthreads();
    }
    if (tid == 0) offs[N] = carry;
    __syncthreads();
    for (int i = tid; i < N; i += 1024) deg[i] = 0;  // re-zero for scatter
}

__global__ void scatter2_kernel(const int* __restrict__ s0, const int* __restrict__ d0,
                                const int* __restrict__ o0, int* __restrict__ c0, int* __restrict__ l0,
                                const int* __restrict__ s1, const int* __restrict__ d1,
                                const int* __restrict__ o1, int* __restrict__ c1, int* __restrict__ l1,
                                int E)
{
    int e = blockIdx.x * blockDim.x + threadIdx.x;
    if (e < E) {
        int d = d0[e];
        int pos = atomicAdd(&c0[d], 1);
        l0[o0[d] + pos] = s0[e];
    } else if (e < 2 * E) {
        int e1 = e - E;
        int d = d1[e1];
        int pos = atomicAdd(&c1[d], 1);
        l1[o1[d] + pos] = s1[e1];
    }
}

// ---------------------------------------------------------------------------
// GAT aggregation, both edge sets: blocks [0,20000) = ap, [20000,40000) = pp
// ---------------------------------------------------------------------------
__global__ __launch_bounds__(64) void gat_agg_all_kernel(
    const ushort* __restrict__ ha, const float* __restrict__ ela, const float* __restrict__ era,
    const int* __restrict__ offsa, const int* __restrict__ lista, const float* __restrict__ biasa,
    const ushort* __restrict__ hp, const float* __restrict__ elp, const float* __restrict__ erp,
    const int* __restrict__ offsp, const int* __restrict__ listp, const float* __restrict__ biasp,
    ushort* __restrict__ out)
{
    int bid = blockIdx.x;
    const ushort* h; const float *el, *er, *bias; const int *offs, *elist;
    int p, dn, coloff;
    if (bid < NP_N) {
        h = ha; el = ela; er = era; offs = offsa; elist = lista; bias = biasa;
        p = bid; dn = NA_N + p; coloff = 256;
    } else {
        h = hp; el = elp; er = erp; offs = offsp; elist = listp; bias = biasp;
        p = bid - NP_N; dn = p; coloff = 512;
    }
    int l = threadIdx.x;
    int head = l >> 3;
    float erv = er[(size_t)dn * 8 + head];
    float acc[4] = {0.f, 0.f, 0.f, 0.f};
    float z = 0.f;
    int beg = offs[p], end = offs[p + 1];
    for (int e = beg - 1; e < end; ++e) {
        int s = (e < beg) ? dn : elist[e];
        float x = el[(size_t)s * 8 + head] + erv;
        x = x > 0.f ? x : 0.2f * x;
        float wgt = expf(x);
        z += wgt;
        ushort4 hv = *(const ushort4*)&h[(size_t)s * 256 + l * 4];
        acc[0] = fmaf(wgt, b2f(hv.x), acc[0]);
        acc[1] = fmaf(wgt, b2f(hv.y), acc[1]);
        acc[2] = fmaf(wgt, b2f(hv.z), acc[2]);
        acc[3] = fmaf(wgt, b2f(hv.w), acc[3]);
    }
    float inv = 1.f / z;
    ushort4 o;
    o.x = f2b(acc[0] * inv + bias[l * 4 + 0]);
    o.y = f2b(acc[1] * inv + bias[l * 4 + 1]);
    o.z = f2b(acc[2] * inv + bias[l * 4 + 2]);
    o.w = f2b(acc[3] * inv + bias[l * 4 + 3]);
    *(ushort4*)&out[(size_t)p * 768 + coloff + l * 4] = o;
}

// ---------------------------------------------------------------------------
// Tiny MHA (S=Sk=3). Writes output IN-PLACE over the q slice (ob may alias
// qb): each thread reads exactly the 32-col q slice it later writes, k/v
// slices are never written. NO __restrict__ (pointers alias by design).
// ---------------------------------------------------------------------------
__global__ void mha3_kernel(const ushort* qb, int ldq, int qoff,
                            const ushort* kvb, int ldkv, int koff, int voff,
                            ushort* ob, int ldo, int NPn)
{
    int idx = blockIdx.x * blockDim.x + threadIdx.x;
    if (idx >= NPn * 24) return;
    int h = idx & 7;
    int i = (idx >> 3) % 3;
    int p = idx / 24;
    float qr[32];
    {
        const ushort* q = qb + (size_t)(p * 3 + i) * ldq + qoff + h * 32;
#pragma unroll
        for (int j = 0; j < 8; ++j) {
            ushort4 t = ((const ushort4*)q)[j];
            qr[j * 4 + 0] = b2f(t.x); qr[j * 4 + 1] = b2f(t.y);
            qr[j * 4 + 2] = b2f(t.z); qr[j * 4 + 3] = b2f(t.w);
        }
    }
    float s[3];
#pragma unroll
    for (int j = 0; j < 3; ++j) {
        const ushort* k = kvb + (size_t)(p * 3 + j) * ldkv + koff + h * 32;
        float a = 0.f;
#pragma unroll
        for (int t4 = 0; t4 < 8; ++t4) {
            ushort4 t = ((const ushort4*)k)[t4];
            a = fmaf(qr[t4 * 4 + 0], b2f(t.x), a);
            a = fmaf(qr[t4 * 4 + 1], b2f(t.y), a);
            a = fmaf(qr[t4 * 4 + 2], b2f(t.z), a);
            a = fmaf(qr[t4 * 4 + 3], b2f(t.w), a);
        }
        s[j] = a * 0.17677669529663687f;
    }
    float m = fmaxf(s[0], fmaxf(s[1], s[2]));
    float e0 = expf(s[0] - m), e1 = expf(s[1] - m), e2 = expf(s[2] - m);
    float inv = 1.f / (e0 + e1 + e2);
    float aw[3] = {e0 * inv, e1 * inv, e2 * inv};
    float o[32] = {};
#pragma unroll
    for (int j = 0; j < 3; ++j) {
        const ushort* v = kvb + (size_t)(p * 3 + j) * ldkv + voff + h * 32;
#pragma unroll
        for (int t4 = 0; t4 < 8; ++t4) {
            ushort4 t = ((const ushort4*)v)[t4];
            o[t4 * 4 + 0] = fmaf(aw[j], b2f(t.x), o[t4 * 4 + 0]);
            o[t4 * 4 + 1] = fmaf(aw[j], b2f(t.y), o[t4 * 4 + 1]);
            o[t4 * 4 + 2] = fmaf(aw[j], b2f(t.z), o[t4 * 4 + 2]);
            o[t4 * 4 + 3] = fmaf(aw[j], b2f(t.w), o[t4 * 4 + 3]);
        }
    }
    ushort* op = ob + (size_t)(p * 3 + i) * ldo + h * 32;
#pragma unroll
    for (int t4 = 0; t4 < 8; ++t4) {
        ushort4 t;
        t.x = f2b(o[t4 * 4 + 0]); t.y = f2b(o[t4 * 4 + 1]);
        t.z = f2b(o[t4 * 4 + 2]); t.w = f2b(o[t4 * 4 + 3]);
        ((ushort4*)op)[t4] = t;
    }
}

// ---------------------------------------------------------------------------
// Fused residual add + LayerNorm (256 ch), bf16, wave/row, in-place safe.
// ---------------------------------------------------------------------------
__global__ __launch_bounds__(256) void add_ln_kernel(
    const ushort* __restrict__ a, const ushort* __restrict__ b,
    const float* __restrict__ g, const float* __restrict__ be,
    ushort* __restrict__ out, int rows)
{
    int row = blockIdx.x * 4 + (threadIdx.x >> 6);
    if (row >= rows) return;
    int l = threadIdx.x & 63;
    ushort4 va = *(const ushort4*)&a[(size_t)row * 256 + l * 4];
    ushort4 vb = *(const ushort4*)&b[(size_t)row * 256 + l * 4];
    float v[4];
    v[0] = b2f(va.x) + b2f(vb.x);
    v[1] = b2f(va.y) + b2f(vb.y);
    v[2] = b2f(va.z) + b2f(vb.z);
    v[3] = b2f(va.w) + b2f(vb.w);
    float s = v[0] + v[1] + v[2] + v[3];
#pragma unroll
    for (int off = 32; off; off >>= 1) s += __shfl_xor(s, off);
    float mean = s * (1.f / 256.f);
    float s2 = 0.f;
#pragma unroll
    for (int j = 0; j < 4; ++j) { float d = v[j] - mean; s2 = fmaf(d, d, s2); }
#pragma unroll
    for (int off = 32; off; off >>= 1) s2 += __shfl_xor(s2, off);
    float rstd = rsqrtf(s2 * (1.f / 256.f) + 1e-5f);
    ushort4 o;
    o.x = f2b((v[0] - mean) * rstd * g[l * 4 + 0] + be[l * 4 + 0]);
    o.y = f2b((v[1] - mean) * rstd * g[l * 4 + 1] + be[l * 4 + 1]);
    o.z = f2b((v[2] - mean) * rstd * g[l * 4 + 2] + be[l * 4 + 2]);
    o.w = f2b((v[3] - mean) * rstd * g[l * 4 + 3] + be[l * 4 + 3]);
    *(ushort4*)&out[(size_t)row * 256 + l * 4] = o;
}

// ---------------------------------------------------------------------------
// kernel_launch — ws layout (bytes), total 184.32 MB (proven safe):
// [0, 30.72M)        tgt_bf
// [30.72M, 61.44M)   X_bf
// [61.44M, 65.28M)   packed weights
// [65.28M, 184.32M)  BIG (era-overlaid; attention eras use <= 92.2 MB)
// ---------------------------------------------------------------------------
extern "C" void kernel_launch(void* const* d_in, const int* in_sizes, int n_in,
                              void* d_out, int out_size, void* d_ws, size_t ws_size,
                              hipStream_t stream)
{
    const float* feat_paper  = (const float*)d_in[0];
    const float* feat_author = (const float*)d_in[1];
    const float* W_in_p  = (const float*)d_in[2];
    const float* b_in_p  = (const float*)d_in[3];
    const float* W_in_a  = (const float*)d_in[4];
    const float* b_in_a  = (const float*)d_in[5];
    const float* W_gat_ap = (const float*)d_in[6];
    const float* al_ap    = (const float*)d_in[7];
    const float* ar_ap    = (const float*)d_in[8];
    const float* b_gat_ap = (const float*)d_in[9];
    const float* W_gat_pp = (const float*)d_in[10];
    const float* al_pp    = (const float*)d_in[11];
    const float* ar_pp    = (const float*)d_in[12];
    const float* b_gat_pp = (const float*)d_in[13];
    const float* Wqkv_s = (const float*)d_in[14];
    const float* bqkv_s = (const float*)d_in[15];
    const float* Wo_s   = (const float*)d_in[16];
    const float* bo_s   = (const float*)d_in[17];
    const float* Wqkv_c = (const float*)d_in[18];
    const float* bqkv_c = (const float*)d_in[19];
    const float* Wo_c   = (const float*)d_in[20];
    const float* bo_c   = (const float*)d_in[21];
    const float* W_ff1  = (const float*)d_in[22];
    const float* b_ff1  = (const float*)d_in[23];
    const float* W_ff2  = (const float*)d_in[24];
    const float* b_ff2  = (const float*)d_in[25];
    const float* ln1_g  = (const float*)d_in[26];
    const float* ln1_b  = (const float*)d_in[27];
    const float* ln2_g  = (const float*)d_in[28];
    const float* ln2_b  = (const float*)d_in[29];
    const float* ln3_g  = (const float*)d_in[30];
    const float* ln3_b  = (const float*)d_in[31];
    const float* W_pred = (const float*)d_in[32];
    const float* b_pred = (const float*)d_in[33];
    const int* ap_src = (const int*)d_in[34];
    const int* ap_dst = (const int*)d_in[35];
    const int* pp_src = (const int*)d_in[36];
    const int* pp_dst = (const int*)d_in[37];

    const int NP = NP_N, NA = NA_N;

    uint8_t* wsb = (uint8_t*)d_ws;
    ushort* tgt_bf = (ushort*)wsb;
    ushort* X_bf   = (ushort*)(wsb + 30720000);
    ushort* WB     = (ushort*)(wsb + 61440000);
    ushort* p_in_p   = WB + 0;
    ushort* p_in_a   = WB + 32768;
    ushort* p_gat_ap = WB + 65536;
    ushort* p_gat_pp = WB + 131072;
    ushort* p_qkv_s  = WB + 196608;
    ushort* p_o_s    = WB + 393216;
    ushort* p_qkv_c  = WB + 458752;
    ushort* p_o_c    = WB + 655360;
    ushort* p_pred   = WB + 720896;
    ushort* p_ff1    = WB + 819200;
    ushort* p_ff2    = WB + 1343488;
    uint8_t* BIG = wsb + 65280000;

    // era A overlay inside BIG
    ushort* feat_p_bf = (ushort*)BIG;
    ushort* feat_a_bf = (ushort*)(BIG + 5120000);
    ushort* x_ap_bf   = (ushort*)(BIG + 10240000);
    ushort* hp_bf     = x_ap_bf + (size_t)NA * 256;
    ushort* h_ap_bf   = (ushort*)(BIG + 30720000);
    ushort* h_pp_bf   = (ushort*)(BIG + 51200000);
    float* el_ap = (float*)(BIG + 61440000);
    float* er_ap = (float*)(BIG + 62720000);
    float* el_pp = (float*)(BIG + 64000000);
    float* er_pp = (float*)(BIG + 64640000);
    int* ireg    = (int*)(BIG + 65280000);
    int* ap_offs = ireg;              // 20001 (pad to 20004)
    int* pp_offs = ireg + 20004;      // 20001 (pad to 20004)
    int* ap_cur  = ireg + 40008;      // 20000
    int* pp_cur  = ireg + 60008;      // 20000 (contiguous with ap_cur)
    int* ap_list = ireg + 80008;      // 400000
    int* pp_list = ireg + 480008;     // 400000

    // ---- mega pack: converts + weight packs + counter zero, ONE dispatch ----
    {
        PackJobs J;
        const float* srcs[NJOBS] = { feat_paper, feat_author, W_in_p, W_in_a, W_gat_ap,
                                     W_gat_pp, Wqkv_s, Wo_s, Wqkv_c, Wo_c, W_pred,
                                     W_ff1, W_ff2, nullptr };
        void* dsts[NJOBS] = { feat_p_bf, feat_a_bf, p_in_p, p_in_a, p_gat_ap,
                              p_gat_pp, p_qkv_s, p_o_s, p_qkv_c, p_o_c, p_pred,
                              p_ff1, p_ff2, ap_cur };
        int Ms[NJOBS]  = {0,0, 256,256,256,256, 768,256,768,256, 64, 0,0, 0};
        int Ks[NJOBS]  = {0,0, 128,128,256,256, 256,256,256,256, 768, 0,0, 0};
        int tys[NJOBS] = {3,3, 0,0,0,0, 0,0,0,0, 0, 1,2, 4};
        int nq[NJOBS]  = {640000,640000, 8192,8192,16384,16384, 49152,16384,49152,16384,
                          24576, 131072,131072, 10000};
        int acc = 0;
        for (int j = 0; j < NJOBS; ++j) {
            J.src[j] = srcs[j]; J.dst[j] = dsts[j];
            J.M[j] = Ms[j]; J.K[j] = Ks[j]; J.type[j] = tys[j]; J.nquad[j] = nq[j];
            J.blk0[j] = acc;
            acc += (nq[j] + 255) / 256;
        }
        pack_all_kernel<<<acc, 256, 0, stream>>>(J);
    }

    // ---- input projections ----
    gemm_bf(feat_a_bf, p_in_a, b_in_a, x_ap_bf, NA, 256, 128, 128, 0, stream);
    gemm_bf(feat_p_bf, p_in_p, b_in_p, hp_bf,   NP, 256, 128, 128, 0, stream);

    copy_col0_kernel<<<(NP * 64 + 255) / 256, 256, 0, stream>>>(hp_bf, tgt_bf, NP * 64);

    // ---- GAT feature transforms ----
    gemm_bf(x_ap_bf, p_gat_ap, nullptr, h_ap_bf, NA + NP, 256, 256, 256, 0, stream);
    gemm_bf(hp_bf,   p_gat_pp, nullptr, h_pp_bf, NP,      256, 256, 256, 0, stream);

    // ---- el/er (one dispatch) ----
    attn_lr_all_kernel<<<1875, 256, 0, stream>>>(h_ap_bf, al_ap, ar_ap, el_ap, er_ap,
                                                 h_pp_bf, al_pp, ar_pp, el_pp, er_pp);

    // ---- CSR build: 3 dispatches ----
    count2_kernel<<<3125, 256, 0, stream>>>(ap_dst, ap_cur, pp_dst, pp_cur, E_AP_N);
    exscan2_kernel<<<2, 1024, 0, stream>>>(ap_cur, ap_offs, pp_cur, pp_offs, NP);
    scatter2_kernel<<<3125, 256, 0, stream>>>(ap_src, ap_dst, ap_offs, ap_cur, ap_list,
                                              pp_src, pp_dst, pp_offs, pp_cur, pp_list, E_AP_N);

    // ---- GAT aggregation (one dispatch) ----
    gat_agg_all_kernel<<<2 * NP, 64, 0, stream>>>(
        h_ap_bf, el_ap, er_ap, ap_offs, ap_list, b_gat_ap,
        h_pp_bf, el_pp, er_pp, pp_offs, pp_list, b_gat_pp, tgt_bf);

    // ---- self attention, full 60000 rows, no extra buffers ----
    {
        ushort* qkv = (ushort*)BIG;  // 92.16 MB
        gemm_bf(tgt_bf, p_qkv_s, bqkv_s, qkv, 60000, 768, 256, 256, 0, stream);
        // mha writes o in-place into the q slice (stride 768)
        mha3_kernel<<<(NP * 24 + 255) / 256, 256, 0, stream>>>(qkv, 768, 0, qkv, 768, 256, 512, qkv, 768, NP);
        // o-proj reads the strided o (lda=768) -> X
        gemm_bf(qkv, p_o_s, bo_s, X_bf, 60000, 256, 256, 768, 0, stream);
        add_ln_kernel<<<15000, 256, 0, stream>>>(tgt_bf, X_bf, ln1_g, ln1_b, X_bf, 60000);
    }

    // ---- cross attention, full 60000 rows ----
    {
        ushort* qb  = (ushort*)BIG;                 // 30.72 MB
        ushort* kvb = (ushort*)(BIG + 30720000);    // 61.44 MB
        const ushort* p_kv_c = p_qkv_c + (size_t)2 * 8 * 4096;  // row-tiles 2..5
        gemm_bf(X_bf,   p_qkv_c, bqkv_c,       qb,  60000, 256, 256, 256, 0, stream);
        gemm_bf(tgt_bf, p_kv_c,  bqkv_c + 256, kvb, 60000, 512, 256, 256, 0, stream);
        mha3_kernel<<<(NP * 24 + 255) / 256, 256, 0, stream>>>(qb, 256, 0, kvb, 512, 0, 256, qb, 256, NP);
        gemm_bf(qb, p_o_c, bo_c, kvb, 60000, 256, 256, 256, 0, stream);  // proj -> kvb (dead)
        add_ln_kernel<<<15000, 256, 0, stream>>>(X_bf, kvb, ln2_g, ln2_b, X_bf, 60000);
    }

    // ---- feed-forward (fused) + LN3 ----
    {
        ushort* ffo = (ushort*)BIG;  // 30.72 MB
        ff_fused_kernel<<<(60000 + 63) / 64, 256, 0, stream>>>(X_bf, p_ff1, p_ff2, b_ff1, b_ff2, ffo, 60000);
        add_ln_kernel<<<15000, 256, 0, stream>>>(X_bf, ffo, ln3_g, ln3_b, X_bf, 60000);
    }

    // ---- prediction head ----
    gemm_bf(X_bf, p_pred, b_pred, (float*)d_out, NP, 64, 768, 768, 1, stream);
}